// Round 1
// baseline (1975.643 us; speedup 1.0000x reference)
//
#include <hip/hip_runtime.h>

// ResContextBlock: 4 sparse subm convs + lrelu + train-mode BN, two branches.
// Strategy: wave-per-voxel, lane=out-channel, skip sentinel neighbors
// (~1.19/9 valid), fold BN1/BN3 affine into W2/W4, BN2/BN4 in final kernel.

#define EPSF 1e-5f

// ---------------- conv (+lrelu +stats) ----------------
// x:[N,CIN]  nbr:[N,9] (sentinel >= N)  Wt:[9][64][CIN] (transposed, maybe scale-folded)
// tvec:[9][64] constant term per valid k (from folded shift), or unused.
// y:[N,64] = lrelu(conv).  stat_sum/sq: [64] accumulated via atomics.
template<int CIN, bool ADD_T>
__global__ __launch_bounds__(256)
void conv_kernel(const float* __restrict__ x,
                 const int* __restrict__ nbr,
                 const float* __restrict__ Wt,
                 const float* __restrict__ tvec,
                 float* __restrict__ y,
                 float* __restrict__ stat_sum,
                 float* __restrict__ stat_sq,
                 int n_vox)
{
    const int lane = threadIdx.x & 63;
    const int wave = threadIdx.x >> 6;
    float psum = 0.f, psq = 0.f;

    for (int n = blockIdx.x * 4 + wave; n < n_vox; n += gridDim.x * 4) {
        float acc = 0.f;
        for (int k = 0; k < 9; ++k) {
            const int idx = nbr[n * 9 + k];
            if (idx >= n_vox) continue;   // sentinel -> zero row, skip
            const float4* __restrict__ xr =
                reinterpret_cast<const float4*>(x + (size_t)idx * CIN);
            const float4* __restrict__ wr =
                reinterpret_cast<const float4*>(Wt + (size_t)(k * 64 + lane) * CIN);
            if (ADD_T) acc += tvec[k * 64 + lane];
            #pragma unroll
            for (int c4 = 0; c4 < CIN / 4; ++c4) {
                float4 xv = xr[c4];
                float4 wv = wr[c4];
                acc = fmaf(xv.x, wv.x, acc);
                acc = fmaf(xv.y, wv.y, acc);
                acc = fmaf(xv.z, wv.z, acc);
                acc = fmaf(xv.w, wv.w, acc);
            }
        }
        float yv = acc > 0.f ? acc : 0.01f * acc;   // leaky relu
        y[(size_t)n * 64 + lane] = yv;
        psum += yv;
        psq  = fmaf(yv, yv, psq);
    }

    __shared__ float ls[4][2][64];
    ls[wave][0][lane] = psum;
    ls[wave][1][lane] = psq;
    __syncthreads();
    if (wave == 0) {
        float s = ls[0][0][lane] + ls[1][0][lane] + ls[2][0][lane] + ls[3][0][lane];
        float q = ls[0][1][lane] + ls[1][1][lane] + ls[2][1][lane] + ls[3][1][lane];
        atomicAdd(&stat_sum[lane], s);
        atomicAdd(&stat_sq[lane], q);
    }
}

// ---------------- BN scale/shift from stats ----------------
__global__ void bnscale_kernel(const float* __restrict__ sum,
                               const float* __restrict__ sq,
                               const float* __restrict__ gamma,
                               const float* __restrict__ beta,
                               float* __restrict__ scale,
                               float* __restrict__ shift,
                               float invN)
{
    int c = threadIdx.x;  // 64 threads
    float m = sum[c] * invN;
    float v = sq[c] * invN - m * m;
    float s = gamma[c] / sqrtf(v + EPSF);
    scale[c] = s;
    shift[c] = beta[c] - m * s;
}

// ---------------- transpose W [9][cin][64] -> Wt [9][64][cin] ----------------
__global__ void transpose_w_kernel(const float* __restrict__ W,
                                   float* __restrict__ Wt, int cin)
{
    int i = blockIdx.x * blockDim.x + threadIdx.x;
    int total = 9 * cin * 64;
    if (i >= total) return;
    int d = i % 64;
    int c = (i / 64) % cin;
    int k = i / (64 * cin);
    Wt[(size_t)(k * 64 + d) * cin + c] = W[i];
}

// ---------------- fold BN affine into W (cin=64) ----------------
// Wtf[k][d][c] = scale[c]*W[k][c][d];  tvec[k][d] = sum_c shift[c]*W[k][c][d]
__global__ void fold_w_kernel(const float* __restrict__ W,
                              const float* __restrict__ scale,
                              const float* __restrict__ shift,
                              float* __restrict__ Wtf,
                              float* __restrict__ tvec)
{
    int i = blockIdx.x * blockDim.x + threadIdx.x;   // 9*64
    if (i >= 9 * 64) return;
    int d = i & 63, k = i >> 6;
    float t = 0.f;
    for (int c = 0; c < 64; ++c) {
        float w = W[(size_t)(k * 64 + c) * 64 + d];
        Wtf[(size_t)(k * 64 + d) * 64 + c] = scale[c] * w;
        t = fmaf(shift[c], w, t);
    }
    tvec[i] = t;
}

// ---------------- final: out = BN2(y2) + BN4(y4) ----------------
__global__ void final_kernel(const float* __restrict__ y2,
                             const float* __restrict__ y4,
                             const float* __restrict__ sc2, const float* __restrict__ sh2,
                             const float* __restrict__ sc4, const float* __restrict__ sh4,
                             float* __restrict__ out, int n_vox)
{
    int i = blockIdx.x * blockDim.x + threadIdx.x;   // over n_vox*16 float4s
    int total = n_vox * 16;
    if (i >= total) return;
    int c = (i & 15) * 4;
    float4 a = reinterpret_cast<const float4*>(y2)[i];
    float4 b = reinterpret_cast<const float4*>(y4)[i];
    float4 r;
    r.x = fmaf(a.x, sc2[c + 0], sh2[c + 0]) + fmaf(b.x, sc4[c + 0], sh4[c + 0]);
    r.y = fmaf(a.y, sc2[c + 1], sh2[c + 1]) + fmaf(b.y, sc4[c + 1], sh4[c + 1]);
    r.z = fmaf(a.z, sc2[c + 2], sh2[c + 2]) + fmaf(b.z, sc4[c + 2], sh4[c + 2]);
    r.w = fmaf(a.w, sc2[c + 3], sh2[c + 3]) + fmaf(b.w, sc4[c + 3], sh4[c + 3]);
    reinterpret_cast<float4*>(out)[i] = r;
}

extern "C" void kernel_launch(void* const* d_in, const int* in_sizes, int n_in,
                              void* d_out, int out_size, void* d_ws, size_t ws_size,
                              hipStream_t stream)
{
    const float* feats  = (const float*)d_in[0];
    const int*   nbr133 = (const int*)d_in[1];
    const int*   nbr313 = (const int*)d_in[2];
    const float* W1 = (const float*)d_in[3];
    const float* W2 = (const float*)d_in[4];
    const float* W3 = (const float*)d_in[5];
    const float* W4 = (const float*)d_in[6];
    const float* g0  = (const float*)d_in[7];
    const float* b0  = (const float*)d_in[8];
    const float* g02 = (const float*)d_in[9];
    const float* b02 = (const float*)d_in[10];
    const float* g1  = (const float*)d_in[11];
    const float* b1  = (const float*)d_in[12];
    const float* g2  = (const float*)d_in[13];
    const float* b2  = (const float*)d_in[14];

    const int N = in_sizes[0] / 32;

    float* wsf = (float*)d_ws;
    const size_t NB = (size_t)N * 64;
    float* bufA = wsf;            // y1, later y3
    float* bufB = wsf + NB;       // y4
    float* Wt1  = wsf + 2 * NB;           // 9*32*64
    float* Wt3  = Wt1 + 9 * 32 * 64;      // 9*32*64
    float* Wt2f = Wt3 + 9 * 32 * 64;      // 9*64*64
    float* Wt4f = Wt2f + 9 * 64 * 64;     // 9*64*64
    float* t2   = Wt4f + 9 * 64 * 64;     // 9*64
    float* t4   = t2 + 9 * 64;            // 9*64
    float* stats = t4 + 9 * 64;           // 8*64: sum1,sq1,sum2,sq2,sum3,sq3,sum4,sq4
    float* sum1 = stats,       *sq1 = stats + 64;
    float* sum2 = stats + 128, *sq2 = stats + 192;
    float* sum3 = stats + 256, *sq3 = stats + 320;
    float* sum4 = stats + 384, *sq4 = stats + 448;
    float* scl = stats + 512;             // 8*64: sc1,sh1,sc2,sh2,sc3,sh3,sc4,sh4
    float* sc1 = scl,       *sh1 = scl + 64;
    float* sc2 = scl + 128, *sh2 = scl + 192;
    float* sc3 = scl + 256, *sh3 = scl + 320;
    float* sc4 = scl + 384, *sh4 = scl + 448;

    hipMemsetAsync(stats, 0, 512 * sizeof(float), stream);

    const int tgrid = (9 * 32 * 64 + 255) / 256;
    transpose_w_kernel<<<tgrid, 256, 0, stream>>>(W1, Wt1, 32);
    transpose_w_kernel<<<tgrid, 256, 0, stream>>>(W3, Wt3, 32);

    const int CG = 2048;
    const float invN = 1.0f / (float)N;

    // shortcut branch, layer 1: conv(feats, nbr133, W1)
    conv_kernel<32, false><<<CG, 256, 0, stream>>>(feats, nbr133, Wt1, nullptr,
                                                   bufA, sum1, sq1, N);
    bnscale_kernel<<<1, 64, 0, stream>>>(sum1, sq1, g0, b0, sc1, sh1, invN);
    fold_w_kernel<<<9, 64, 0, stream>>>(W2, sc1, sh1, Wt2f, t2);
    // layer 2: conv(BN1(y1), nbr313, W2) -> y2 in d_out (scratch use)
    conv_kernel<64, true><<<CG, 256, 0, stream>>>(bufA, nbr313, Wt2f, t2,
                                                  (float*)d_out, sum2, sq2, N);

    // resA branch, layer 3: conv(feats, nbr313, W3) -> bufA (y1 dead)
    conv_kernel<32, false><<<CG, 256, 0, stream>>>(feats, nbr313, Wt3, nullptr,
                                                   bufA, sum3, sq3, N);
    bnscale_kernel<<<1, 64, 0, stream>>>(sum3, sq3, g1, b1, sc3, sh3, invN);
    fold_w_kernel<<<9, 64, 0, stream>>>(W4, sc3, sh3, Wt4f, t4);
    // layer 4: conv(BN3(y3), nbr133, W4) -> bufB
    conv_kernel<64, true><<<CG, 256, 0, stream>>>(bufA, nbr133, Wt4f, t4,
                                                  bufB, sum4, sq4, N);

    bnscale_kernel<<<1, 64, 0, stream>>>(sum2, sq2, g02, b02, sc2, sh2, invN);
    bnscale_kernel<<<1, 64, 0, stream>>>(sum4, sq4, g2, b2, sc4, sh4, invN);

    const int fgrid = (N * 16 + 255) / 256;
    final_kernel<<<fgrid, 256, 0, stream>>>((const float*)d_out, bufB,
                                            sc2, sh2, sc4, sh4,
                                            (float*)d_out, N);
}

// Round 2
// 742.686 us; speedup vs baseline: 2.6601x; 2.6601x over previous
//
#include <hip/hip_runtime.h>

// ResContextBlock: 4 sparse subm convs + lrelu + train-mode BN, two branches.
// R2: center-tap dense GEMV (8 voxels/wave-iter, W-center in registers) +
// ballot-compacted rare off-center taps; conv1+conv3 fused (share feats read).

#define EPSF 1e-5f

__device__ __forceinline__ float dot4(float4 a, float4 b, float acc) {
    acc = fmaf(a.x, b.x, acc);
    acc = fmaf(a.y, b.y, acc);
    acc = fmaf(a.z, b.z, acc);
    acc = fmaf(a.w, b.w, acc);
    return acc;
}

// ---------------- fused conv1+conv3 (CIN=32, no tvec) ----------------
// x:[N,32]; nbrA/nbrB:[N,9] sentinel>=N; WtA/WtB:[9][64][32] transposed.
// yA/yB = lrelu(conv); stats: [sumA|sqA|sumB|sqB] 4x64, atomically accumulated.
template<int CIN>
__global__ __launch_bounds__(256)
void conv13_kernel(const float* __restrict__ x,
                   const int* __restrict__ nbrA,
                   const int* __restrict__ nbrB,
                   const float* __restrict__ WtA,
                   const float* __restrict__ WtB,
                   float* __restrict__ yA,
                   float* __restrict__ yB,
                   float* __restrict__ stats,
                   int n_vox)
{
    constexpr int C4 = CIN / 4;
    const int lane = threadIdx.x & 63;
    const int wave = threadIdx.x >> 6;

    // center-tap W columns in registers
    float4 wA[C4], wB[C4];
    {
        const float4* a = reinterpret_cast<const float4*>(WtA + (size_t)(4*64 + lane) * CIN);
        const float4* b = reinterpret_cast<const float4*>(WtB + (size_t)(4*64 + lane) * CIN);
        #pragma unroll
        for (int c = 0; c < C4; ++c) { wA[c] = a[c]; wB[c] = b[c]; }
    }

    float psumA = 0.f, psqA = 0.f, psumB = 0.f, psqB = 0.f;

    const int vsub = lane >> 3;                 // voxel-in-tile this lane probes
    const int jj = lane & 7;
    const int kk = jj + (jj >= 4 ? 1 : 0);      // off-center k in {0..3,5..8}

    const int nTiles = (n_vox + 7) >> 3;
    for (int t = blockIdx.x * 4 + wave; t < nTiles; t += gridDim.x * 4) {
        const int n0 = t << 3;
        const int nv = n0 + vsub;
        const bool inb = nv < n_vox;
        int idxA = inb ? nbrA[(size_t)nv * 9 + kk] : n_vox;
        int idxB = inb ? nbrB[(size_t)nv * 9 + kk] : n_vox;
        unsigned long long mA = __ballot(idxA < n_vox);
        unsigned long long mB = __ballot(idxB < n_vox);

        float accA[8], accB[8];
        #pragma unroll
        for (int v = 0; v < 8; ++v) { accA[v] = 0.f; accB[v] = 0.f; }

        // dense center tap: 8 independent chains
        #pragma unroll
        for (int v = 0; v < 8; ++v) {
            if (n0 + v < n_vox) {
                const float4* xr = reinterpret_cast<const float4*>(x + (size_t)(n0 + v) * CIN);
                #pragma unroll
                for (int c = 0; c < C4; ++c) {
                    float4 xv = xr[c];
                    accA[v] = dot4(xv, wA[c], accA[v]);
                    accB[v] = dot4(xv, wB[c], accB[v]);
                }
            }
        }

        // rare off-center taps (avg ~0.19/voxel each conv)
        #pragma unroll
        for (int v = 0; v < 8; ++v) {
            unsigned int sA = (unsigned int)(mA >> (v * 8)) & 0xffu;
            while (sA) {
                int b = __builtin_ctz(sA); sA &= sA - 1;
                int src = __shfl(idxA, v * 8 + b);
                int k = b + (b >= 4 ? 1 : 0);
                const float4* xr = reinterpret_cast<const float4*>(x + (size_t)src * CIN);
                const float4* wr = reinterpret_cast<const float4*>(WtA + (size_t)(k*64 + lane) * CIN);
                float a = 0.f;
                #pragma unroll
                for (int c = 0; c < C4; ++c) a = dot4(xr[c], wr[c], a);
                accA[v] += a;
            }
            unsigned int sB = (unsigned int)(mB >> (v * 8)) & 0xffu;
            while (sB) {
                int b = __builtin_ctz(sB); sB &= sB - 1;
                int src = __shfl(idxB, v * 8 + b);
                int k = b + (b >= 4 ? 1 : 0);
                const float4* xr = reinterpret_cast<const float4*>(x + (size_t)src * CIN);
                const float4* wr = reinterpret_cast<const float4*>(WtB + (size_t)(k*64 + lane) * CIN);
                float a = 0.f;
                #pragma unroll
                for (int c = 0; c < C4; ++c) a = dot4(xr[c], wr[c], a);
                accB[v] += a;
            }
        }

        // epilogue: lrelu, store, stats
        #pragma unroll
        for (int v = 0; v < 8; ++v) {
            if (n0 + v < n_vox) {
                float a = accA[v]; a = a > 0.f ? a : 0.01f * a;
                yA[(size_t)(n0 + v) * 64 + lane] = a;
                psumA += a; psqA = fmaf(a, a, psqA);
                float bq = accB[v]; bq = bq > 0.f ? bq : 0.01f * bq;
                yB[(size_t)(n0 + v) * 64 + lane] = bq;
                psumB += bq; psqB = fmaf(bq, bq, psqB);
            }
        }
    }

    __shared__ float ls[4][4][64];
    ls[wave][0][lane] = psumA; ls[wave][1][lane] = psqA;
    ls[wave][2][lane] = psumB; ls[wave][3][lane] = psqB;
    __syncthreads();
    if (wave == 0) {
        #pragma unroll
        for (int s = 0; s < 4; ++s)
            atomicAdd(&stats[s * 64 + lane],
                      ls[0][s][lane] + ls[1][s][lane] + ls[2][s][lane] + ls[3][s][lane]);
    }
}

// ---------------- single conv (CIN=64, +tvec, BN-folded W) ----------------
template<int CIN>
__global__ __launch_bounds__(256)
void conv24_kernel(const float* __restrict__ x,
                   const int* __restrict__ nbr,
                   const float* __restrict__ Wt,
                   const float* __restrict__ tvec,
                   float* __restrict__ y,
                   float* __restrict__ stats,   // [sum|sq]
                   int n_vox)
{
    constexpr int C4 = CIN / 4;
    const int lane = threadIdx.x & 63;
    const int wave = threadIdx.x >> 6;

    float4 wC[C4];
    {
        const float4* a = reinterpret_cast<const float4*>(Wt + (size_t)(4*64 + lane) * CIN);
        #pragma unroll
        for (int c = 0; c < C4; ++c) wC[c] = a[c];
    }
    const float tC = tvec[4 * 64 + lane];

    float psum = 0.f, psq = 0.f;

    const int vsub = lane >> 3;
    const int jj = lane & 7;
    const int kk = jj + (jj >= 4 ? 1 : 0);

    const int nTiles = (n_vox + 7) >> 3;
    for (int t = blockIdx.x * 4 + wave; t < nTiles; t += gridDim.x * 4) {
        const int n0 = t << 3;
        const int nv = n0 + vsub;
        const bool inb = nv < n_vox;
        int idx = inb ? nbr[(size_t)nv * 9 + kk] : n_vox;
        unsigned long long m = __ballot(idx < n_vox);

        float acc[8];
        #pragma unroll
        for (int v = 0; v < 8; ++v) acc[v] = tC;   // center always valid

        #pragma unroll
        for (int v = 0; v < 8; ++v) {
            if (n0 + v < n_vox) {
                const float4* xr = reinterpret_cast<const float4*>(x + (size_t)(n0 + v) * CIN);
                #pragma unroll
                for (int c = 0; c < C4; ++c)
                    acc[v] = dot4(xr[c], wC[c], acc[v]);
            }
        }

        #pragma unroll
        for (int v = 0; v < 8; ++v) {
            unsigned int s = (unsigned int)(m >> (v * 8)) & 0xffu;
            while (s) {
                int b = __builtin_ctz(s); s &= s - 1;
                int src = __shfl(idx, v * 8 + b);
                int k = b + (b >= 4 ? 1 : 0);
                const float4* xr = reinterpret_cast<const float4*>(x + (size_t)src * CIN);
                const float4* wr = reinterpret_cast<const float4*>(Wt + (size_t)(k*64 + lane) * CIN);
                float a = tvec[k * 64 + lane];
                #pragma unroll
                for (int c = 0; c < C4; ++c) a = dot4(xr[c], wr[c], a);
                acc[v] += a;
            }
        }

        #pragma unroll
        for (int v = 0; v < 8; ++v) {
            if (n0 + v < n_vox) {
                float a = acc[v]; a = a > 0.f ? a : 0.01f * a;
                y[(size_t)(n0 + v) * 64 + lane] = a;
                psum += a; psq = fmaf(a, a, psq);
            }
        }
    }

    __shared__ float ls[4][2][64];
    ls[wave][0][lane] = psum; ls[wave][1][lane] = psq;
    __syncthreads();
    if (wave == 0) {
        atomicAdd(&stats[lane],      ls[0][0][lane]+ls[1][0][lane]+ls[2][0][lane]+ls[3][0][lane]);
        atomicAdd(&stats[64 + lane], ls[0][1][lane]+ls[1][1][lane]+ls[2][1][lane]+ls[3][1][lane]);
    }
}

// ---------------- BN scale/shift from stats (two sets per launch) ----------------
__global__ void bnscale2_kernel(const float* __restrict__ sumA, const float* __restrict__ sqA,
                                const float* __restrict__ gA, const float* __restrict__ bA,
                                float* __restrict__ scA, float* __restrict__ shA,
                                const float* __restrict__ sumB, const float* __restrict__ sqB,
                                const float* __restrict__ gB, const float* __restrict__ bB,
                                float* __restrict__ scB, float* __restrict__ shB,
                                float invN)
{
    int c = threadIdx.x & 63;
    const float* sum = threadIdx.x < 64 ? sumA : sumB;
    const float* sq  = threadIdx.x < 64 ? sqA  : sqB;
    const float* g   = threadIdx.x < 64 ? gA   : gB;
    const float* b   = threadIdx.x < 64 ? bA   : bB;
    float* sc        = threadIdx.x < 64 ? scA  : scB;
    float* sh        = threadIdx.x < 64 ? shA  : shB;
    float m = sum[c] * invN;
    float v = sq[c] * invN - m * m;
    float s = g[c] / sqrtf(v + EPSF);
    sc[c] = s;
    sh[c] = b[c] - m * s;
}

// ---------------- transpose W1,W3 [9][32][64] -> [9][64][32] ----------------
__global__ void transpose_w_kernel(const float* __restrict__ W1, float* __restrict__ Wt1,
                                   const float* __restrict__ W3, float* __restrict__ Wt3)
{
    int i = blockIdx.x * blockDim.x + threadIdx.x;
    const int total = 9 * 32 * 64;
    if (i >= 2 * total) return;
    const float* W = i < total ? W1 : W3;
    float* Wt = i < total ? Wt1 : Wt3;
    int ii = i < total ? i : i - total;
    int d = ii % 64;
    int c = (ii / 64) % 32;
    int k = ii / (64 * 32);
    Wt[(size_t)(k * 64 + d) * 32 + c] = W[ii];
}

// ---------------- fold BN affine into W2 & W4 (cin=64) ----------------
__global__ void fold_w_kernel(const float* __restrict__ W2,
                              const float* __restrict__ sc1, const float* __restrict__ sh1,
                              float* __restrict__ Wt2f, float* __restrict__ t2,
                              const float* __restrict__ W4,
                              const float* __restrict__ sc3, const float* __restrict__ sh3,
                              float* __restrict__ Wt4f, float* __restrict__ t4)
{
    int i = blockIdx.x * blockDim.x + threadIdx.x;   // 2 * 9*64
    if (i >= 2 * 9 * 64) return;
    const float* W = i < 9*64 ? W2 : W4;
    const float* scale = i < 9*64 ? sc1 : sc3;
    const float* shift = i < 9*64 ? sh1 : sh3;
    float* Wtf = i < 9*64 ? Wt2f : Wt4f;
    float* tv  = i < 9*64 ? t2   : t4;
    int ii = i < 9*64 ? i : i - 9*64;
    int d = ii & 63, k = ii >> 6;
    float t = 0.f;
    for (int c = 0; c < 64; ++c) {
        float w = W[(size_t)(k * 64 + c) * 64 + d];
        Wtf[(size_t)(k * 64 + d) * 64 + c] = scale[c] * w;
        t = fmaf(shift[c], w, t);
    }
    tv[ii] = t;
}

// ---------------- final: out = BN2(y2) + BN4(y4) ----------------
__global__ void final_kernel(const float* __restrict__ y2,
                             const float* __restrict__ y4,
                             const float* __restrict__ sc2, const float* __restrict__ sh2,
                             const float* __restrict__ sc4, const float* __restrict__ sh4,
                             float* __restrict__ out, int n_vox)
{
    int i = blockIdx.x * blockDim.x + threadIdx.x;   // over n_vox*16 float4s
    int total = n_vox * 16;
    if (i >= total) return;
    int c = (i & 15) * 4;
    float4 a = reinterpret_cast<const float4*>(y2)[i];
    float4 b = reinterpret_cast<const float4*>(y4)[i];
    float4 r;
    r.x = fmaf(a.x, sc2[c + 0], sh2[c + 0]) + fmaf(b.x, sc4[c + 0], sh4[c + 0]);
    r.y = fmaf(a.y, sc2[c + 1], sh2[c + 1]) + fmaf(b.y, sc4[c + 1], sh4[c + 1]);
    r.z = fmaf(a.z, sc2[c + 2], sh2[c + 2]) + fmaf(b.z, sc4[c + 2], sh4[c + 2]);
    r.w = fmaf(a.w, sc2[c + 3], sh2[c + 3]) + fmaf(b.w, sc4[c + 3], sh4[c + 3]);
    reinterpret_cast<float4*>(out)[i] = r;
}

extern "C" void kernel_launch(void* const* d_in, const int* in_sizes, int n_in,
                              void* d_out, int out_size, void* d_ws, size_t ws_size,
                              hipStream_t stream)
{
    const float* feats  = (const float*)d_in[0];
    const int*   nbr133 = (const int*)d_in[1];
    const int*   nbr313 = (const int*)d_in[2];
    const float* W1 = (const float*)d_in[3];
    const float* W2 = (const float*)d_in[4];
    const float* W3 = (const float*)d_in[5];
    const float* W4 = (const float*)d_in[6];
    const float* g0  = (const float*)d_in[7];
    const float* b0  = (const float*)d_in[8];
    const float* g02 = (const float*)d_in[9];
    const float* b02 = (const float*)d_in[10];
    const float* g1  = (const float*)d_in[11];
    const float* b1  = (const float*)d_in[12];
    const float* g2  = (const float*)d_in[13];
    const float* b2  = (const float*)d_in[14];

    const int N = in_sizes[0] / 32;

    float* wsf = (float*)d_ws;
    const size_t NB = (size_t)N * 64;
    float* bufA = wsf;                    // y1, later y4
    float* bufB = wsf + NB;               // y3
    float* Wt1  = wsf + 2 * NB;           // 9*64*32
    float* Wt3  = Wt1 + 9 * 64 * 32;      // 9*64*32
    float* Wt2f = Wt3 + 9 * 64 * 32;      // 9*64*64
    float* Wt4f = Wt2f + 9 * 64 * 64;     // 9*64*64
    float* t2   = Wt4f + 9 * 64 * 64;     // 9*64
    float* t4   = t2 + 9 * 64;            // 9*64
    float* stats = t4 + 9 * 64;           // 8*64
    float* sum1 = stats,       *sq1 = stats + 64;
    float* sum3 = stats + 128, *sq3 = stats + 192;
    float* st2  = stats + 256;            // sum2|sq2
    float* st4  = stats + 384;            // sum4|sq4
    float* scl = stats + 512;             // 8*64
    float* sc1 = scl,       *sh1 = scl + 64;
    float* sc3 = scl + 128, *sh3 = scl + 192;
    float* sc2 = scl + 256, *sh2 = scl + 320;
    float* sc4 = scl + 384, *sh4 = scl + 448;

    hipMemsetAsync(stats, 0, 512 * sizeof(float), stream);

    transpose_w_kernel<<<(2 * 9 * 32 * 64 + 255) / 256, 256, 0, stream>>>(W1, Wt1, W3, Wt3);

    const float invN = 1.0f / (float)N;
    const int nTiles = (N + 7) / 8;
    const int cblocks = (nTiles + 4 * 8 - 1) / (4 * 8);   // each wave ~8 tiles

    // conv1 + conv3 fused (read feats once)
    conv13_kernel<32><<<cblocks, 256, 0, stream>>>(feats, nbr133, nbr313, Wt1, Wt3,
                                                   bufA, bufB, stats, N);
    // BN1, BN3 scale/shift; fold into W2, W4
    bnscale2_kernel<<<1, 128, 0, stream>>>(sum1, sq1, g0, b0, sc1, sh1,
                                           sum3, sq3, g1, b1, sc3, sh3, invN);
    fold_w_kernel<<<(2 * 9 * 64 + 255) / 256, 256, 0, stream>>>(
        W2, sc1, sh1, Wt2f, t2, W4, sc3, sh3, Wt4f, t4);

    // conv2: y2 -> d_out (scratch); conv4: y4 -> bufA (y1 dead after conv2)
    conv24_kernel<64><<<cblocks, 256, 0, stream>>>(bufA, nbr313, Wt2f, t2,
                                                   (float*)d_out, st2, N);
    conv24_kernel<64><<<cblocks, 256, 0, stream>>>(bufB, nbr133, Wt4f, t4,
                                                   bufA, st4, N);

    bnscale2_kernel<<<1, 128, 0, stream>>>(st2, st2 + 64, g02, b02, sc2, sh2,
                                           st4, st4 + 64, g2, b2, sc4, sh4, invN);

    final_kernel<<<(N * 16 + 255) / 256, 256, 0, stream>>>(
        (const float*)d_out, bufA, sc2, sh2, sc4, sh4, (float*)d_out, N);
}

// Round 3
// 422.076 us; speedup vs baseline: 4.6808x; 1.7596x over previous
//
#include <hip/hip_runtime.h>

// ResContextBlock R3: center tap as bf16 MFMA GEMM (16x16x32), off-center rare
// taps via ballot + VALU dot + shuffle-inject into MFMA C-layout.
// Intermediates y1,y3,y4 bf16; y2 fp32 in d_out; BN folded; deterministic
// partial-sum stats (no atomics).

typedef __attribute__((ext_vector_type(8))) short bf16x8;
typedef __attribute__((ext_vector_type(4))) float f32x4;

#define EPSF 1e-5f
#define NBLK 1024

__device__ __forceinline__ unsigned short f2bf(float f) {
    unsigned int u = __float_as_uint(f);
    u = (u + 0x7fffu + ((u >> 16) & 1u)) >> 16;   // RNE
    return (unsigned short)u;
}
__device__ __forceinline__ float dot4(float4 a, float4 b, float acc) {
    acc = fmaf(a.x, b.x, acc);
    acc = fmaf(a.y, b.y, acc);
    acc = fmaf(a.z, b.z, acc);
    acc = fmaf(a.w, b.w, acc);
    return acc;
}

// ---------- prep: transpose W1,W3 -> Wt[9][64][32]; pack center B-frags ----------
__global__ void prep_kernel(const float* __restrict__ W1, const float* __restrict__ W3,
                            float* __restrict__ Wt1, float* __restrict__ Wt3,
                            unsigned short* __restrict__ Wb1, unsigned short* __restrict__ Wb3)
{
    int i = blockIdx.x * 256 + threadIdx.x;
    const int TT = 9 * 32 * 64;
    if (i < 2 * TT) {
        const float* W = i < TT ? W1 : W3;
        float* Wt = i < TT ? Wt1 : Wt3;
        int ii = i < TT ? i : i - TT;
        int d = ii % 64, c = (ii / 64) % 32, k = ii / (64 * 32);
        Wt[(size_t)(k * 64 + d) * 32 + c] = W[ii];
    } else {
        int p = i - 2 * TT;                 // 2 * 2048 pack jobs
        if (p >= 2 * 2048) return;
        const float* W = p < 2048 ? W1 : W3;
        unsigned short* Wb = p < 2048 ? Wb1 : Wb3;
        int pp = p & 2047;                  // ((t*64+lane)*8+j)
        int j = pp & 7, lane = (pp >> 3) & 63, t = pp >> 9;
        int c = (lane >> 4) * 8 + j;        // k (cin), kt=0
        int d = t * 16 + (lane & 15);
        Wb[pp] = f2bf(W[(size_t)(4 * 32 + c) * 64 + d]);   // center tap k=4
    }
}

// ---------- fused conv1+conv3 (CIN=32, fp32 feats in, bf16 y out) ----------
__global__ __launch_bounds__(256)
void conv13_kernel(const float* __restrict__ x,
                   const int* __restrict__ nbrA,     // 133
                   const int* __restrict__ nbrB,     // 313
                   const float* __restrict__ WtA,    // [9][64][32]
                   const float* __restrict__ WtB,
                   const unsigned short* __restrict__ WbA,
                   const unsigned short* __restrict__ WbB,
                   unsigned short* __restrict__ yA,  // bf16 [N][64]
                   unsigned short* __restrict__ yB,
                   float* __restrict__ part,         // [4*64][NBLK]
                   int n_vox)
{
    const int lane = threadIdx.x & 63;
    const int wave = threadIdx.x >> 6;
    __shared__ float stage[4][1088];                 // per-wave [16][68] + stats reuse

    bf16x8 bA[4], bB[4];
    #pragma unroll
    for (int t = 0; t < 4; ++t) {
        bA[t] = *reinterpret_cast<const bf16x8*>(WbA + (t * 64 + lane) * 8);
        bB[t] = *reinterpret_cast<const bf16x8*>(WbB + (t * 64 + lane) * 8);
    }

    float psA0[4] = {0,0,0,0}, psA1[4] = {0,0,0,0};
    float psB0[4] = {0,0,0,0}, psB1[4] = {0,0,0,0};

    const int j7 = lane & 7;
    const int kk = j7 + (j7 >= 4 ? 1 : 0);
    const int vv = lane >> 3;
    const int c15 = lane & 15;
    const int g16 = lane >> 4;

    const int ntile = n_vox >> 6;                    // N divisible by 64 (200000)
    for (int tile = blockIdx.x; tile < ntile; tile += gridDim.x) {
        const int v16 = tile * 64 + wave * 16;

        // A fragment: fp32 -> bf16
        const float* xr = x + (size_t)(v16 + c15) * 32 + (g16 * 8);
        float4 x0 = *reinterpret_cast<const float4*>(xr);
        float4 x1 = *reinterpret_cast<const float4*>(xr + 4);
        bf16x8 af;
        af[0] = (short)f2bf(x0.x); af[1] = (short)f2bf(x0.y);
        af[2] = (short)f2bf(x0.z); af[3] = (short)f2bf(x0.w);
        af[4] = (short)f2bf(x1.x); af[5] = (short)f2bf(x1.y);
        af[6] = (short)f2bf(x1.z); af[7] = (short)f2bf(x1.w);

        // probes (issue early)
        const size_t r0 = (size_t)(v16 + vv) * 9 + kk;
        const size_t r1 = (size_t)(v16 + 8 + vv) * 9 + kk;
        int iA0 = nbrA[r0], iA1 = nbrA[r1];
        int iB0 = nbrB[r0], iB1 = nbrB[r1];

        f32x4 accA[4], accB[4];
        #pragma unroll
        for (int t = 0; t < 4; ++t) {
            f32x4 z = {0.f, 0.f, 0.f, 0.f};
            accA[t] = z; accB[t] = z;
        }
        #pragma unroll
        for (int t = 0; t < 4; ++t) {
            accA[t] = __builtin_amdgcn_mfma_f32_16x16x32_bf16(af, bA[t], accA[t], 0, 0, 0);
            accB[t] = __builtin_amdgcn_mfma_f32_16x16x32_bf16(af, bB[t], accB[t], 0, 0, 0);
        }

        unsigned long long mA0 = __ballot(iA0 < n_vox);
        unsigned long long mA1 = __ballot(iA1 < n_vox);
        unsigned long long mB0 = __ballot(iB0 < n_vox);
        unsigned long long mB1 = __ballot(iB1 < n_vox);

        auto offc = [&](unsigned long long m, int idxv, const float* Wt, f32x4* acc, int vbase) {
            while (m) {
                int b = __builtin_ctzll(m); m &= m - 1;
                int src = __shfl(idxv, b);
                int bj = b & 7;
                int k = bj + (bj >= 4 ? 1 : 0);
                int v = vbase + (b >> 3);
                const float* wr = Wt + (size_t)(k * 64 + lane) * 32;
                const float* xs = x + (size_t)src * 32;
                float contrib = 0.f;
                #pragma unroll
                for (int c4 = 0; c4 < 8; ++c4) {
                    float4 wv = *reinterpret_cast<const float4*>(wr + c4 * 4);
                    float4 xv = *reinterpret_cast<const float4*>(xs + c4 * 4);
                    contrib = dot4(xv, wv, contrib);
                }
                int g = v >> 2, jj = v & 3;
                #pragma unroll
                for (int t = 0; t < 4; ++t) {
                    float val = __shfl(contrib, t * 16 + c15);
                    if (g16 == g) {
                        if (jj == 0) acc[t][0] += val;
                        else if (jj == 1) acc[t][1] += val;
                        else if (jj == 2) acc[t][2] += val;
                        else acc[t][3] += val;
                    }
                }
            }
        };
        offc(mA0, iA0, WtA, accA, 0);
        offc(mA1, iA1, WtA, accA, 8);
        offc(mB0, iB0, WtB, accB, 0);
        offc(mB1, iB1, WtB, accB, 8);

        auto epi = [&](f32x4* acc, float* ps0, float* ps1, unsigned short* yo) {
            float* stg = stage[wave];
            #pragma unroll
            for (int t = 0; t < 4; ++t) {
                const int col = t * 16 + c15;
                #pragma unroll
                for (int j = 0; j < 4; ++j) {
                    float v = acc[t][j];
                    v = v > 0.f ? v : 0.01f * v;          // leaky relu
                    ps0[t] += v;
                    ps1[t] = fmaf(v, v, ps1[t]);
                    stg[(g16 * 4 + j) * 68 + col] = v;
                }
            }
            const int mm = lane >> 2, cc0 = (lane & 3) * 16;
            float4 q0 = *reinterpret_cast<float4*>(&stg[mm * 68 + cc0]);
            float4 q1 = *reinterpret_cast<float4*>(&stg[mm * 68 + cc0 + 4]);
            float4 q2 = *reinterpret_cast<float4*>(&stg[mm * 68 + cc0 + 8]);
            float4 q3 = *reinterpret_cast<float4*>(&stg[mm * 68 + cc0 + 12]);
            uint4 o0, o1;
            o0.x = f2bf(q0.x) | ((unsigned)f2bf(q0.y) << 16);
            o0.y = f2bf(q0.z) | ((unsigned)f2bf(q0.w) << 16);
            o0.z = f2bf(q1.x) | ((unsigned)f2bf(q1.y) << 16);
            o0.w = f2bf(q1.z) | ((unsigned)f2bf(q1.w) << 16);
            o1.x = f2bf(q2.x) | ((unsigned)f2bf(q2.y) << 16);
            o1.y = f2bf(q2.z) | ((unsigned)f2bf(q2.w) << 16);
            o1.z = f2bf(q3.x) | ((unsigned)f2bf(q3.y) << 16);
            o1.w = f2bf(q3.z) | ((unsigned)f2bf(q3.w) << 16);
            uint4* dst = reinterpret_cast<uint4*>(yo + (size_t)(v16 + mm) * 64 + cc0);
            dst[0] = o0; dst[1] = o1;
        };
        epi(accA, psA0, psA1, yA);
        epi(accB, psB0, psB1, yB);
    }

    __syncthreads();
    float* lsf = &stage[0][0];                       // reuse as [16][256]
    const int r = wave * 4 + g16;
    #pragma unroll
    for (int t = 0; t < 4; ++t) {
        lsf[r * 256 + 0 * 64 + t * 16 + c15] = psA0[t];
        lsf[r * 256 + 1 * 64 + t * 16 + c15] = psA1[t];
        lsf[r * 256 + 2 * 64 + t * 16 + c15] = psB0[t];
        lsf[r * 256 + 3 * 64 + t * 16 + c15] = psB1[t];
    }
    __syncthreads();
    const int tid = threadIdx.x;
    float s = 0.f;
    #pragma unroll
    for (int rr = 0; rr < 16; ++rr) s += lsf[rr * 256 + tid];
    part[(size_t)tid * NBLK + blockIdx.x] = s;
}

// ---------- conv2/conv4 (CIN=64 bf16 in, folded W; out fp32 or bf16) ----------
template<bool OUTF32>
__global__ __launch_bounds__(256)
void conv24_kernel(const unsigned short* __restrict__ x,   // bf16 [N][64]
                   const int* __restrict__ nbr,
                   const float* __restrict__ Wt,           // [9][64][64] scale-folded
                   const float* __restrict__ tvec,         // [9][64]
                   const unsigned short* __restrict__ Wb,  // [2][4][64][8]
                   void* __restrict__ yout,
                   float* __restrict__ part,               // [2*64][NBLK]
                   int n_vox)
{
    const int lane = threadIdx.x & 63;
    const int wave = threadIdx.x >> 6;
    __shared__ float stage[4][1088];

    bf16x8 bw[2][4];
    #pragma unroll
    for (int kt = 0; kt < 2; ++kt)
        #pragma unroll
        for (int t = 0; t < 4; ++t)
            bw[kt][t] = *reinterpret_cast<const bf16x8*>(Wb + ((kt * 4 + t) * 64 + lane) * 8);

    const int c15 = lane & 15, g16 = lane >> 4;
    float tC[4];
    #pragma unroll
    for (int t = 0; t < 4; ++t) tC[t] = tvec[4 * 64 + t * 16 + c15];

    float ps0[4] = {0,0,0,0}, ps1[4] = {0,0,0,0};
    const int j7 = lane & 7;
    const int kk = j7 + (j7 >= 4 ? 1 : 0);
    const int vv = lane >> 3;

    const int ntile = n_vox >> 6;
    for (int tile = blockIdx.x; tile < ntile; tile += gridDim.x) {
        const int v16 = tile * 64 + wave * 16;
        const unsigned short* xr = x + (size_t)(v16 + c15) * 64 + g16 * 8;
        bf16x8 a0 = *reinterpret_cast<const bf16x8*>(xr);
        bf16x8 a1 = *reinterpret_cast<const bf16x8*>(xr + 32);

        const size_t r0 = (size_t)(v16 + vv) * 9 + kk;
        const size_t r1 = (size_t)(v16 + 8 + vv) * 9 + kk;
        int i0 = nbr[r0], i1 = nbr[r1];

        f32x4 acc[4];
        #pragma unroll
        for (int t = 0; t < 4; ++t) {
            f32x4 z = {tC[t], tC[t], tC[t], tC[t]};
            acc[t] = z;
        }
        #pragma unroll
        for (int t = 0; t < 4; ++t) {
            acc[t] = __builtin_amdgcn_mfma_f32_16x16x32_bf16(a0, bw[0][t], acc[t], 0, 0, 0);
            acc[t] = __builtin_amdgcn_mfma_f32_16x16x32_bf16(a1, bw[1][t], acc[t], 0, 0, 0);
        }

        unsigned long long m0 = __ballot(i0 < n_vox);
        unsigned long long m1 = __ballot(i1 < n_vox);

        auto offc = [&](unsigned long long m, int idxv, int vbase) {
            while (m) {
                int b = __builtin_ctzll(m); m &= m - 1;
                int src = __shfl(idxv, b);
                int bj = b & 7;
                int k = bj + (bj >= 4 ? 1 : 0);
                int v = vbase + (b >> 3);
                const float* wr = Wt + (size_t)(k * 64 + lane) * 64;
                const unsigned short* xs = x + (size_t)src * 64;
                float contrib = tvec[k * 64 + lane];
                #pragma unroll
                for (int q = 0; q < 8; ++q) {
                    uint4 xq = *reinterpret_cast<const uint4*>(xs + q * 8);
                    float4 w0 = *reinterpret_cast<const float4*>(wr + q * 8);
                    float4 w1 = *reinterpret_cast<const float4*>(wr + q * 8 + 4);
                    contrib = fmaf(__uint_as_float(xq.x << 16), w0.x, contrib);
                    contrib = fmaf(__uint_as_float(xq.x & 0xffff0000u), w0.y, contrib);
                    contrib = fmaf(__uint_as_float(xq.y << 16), w0.z, contrib);
                    contrib = fmaf(__uint_as_float(xq.y & 0xffff0000u), w0.w, contrib);
                    contrib = fmaf(__uint_as_float(xq.z << 16), w1.x, contrib);
                    contrib = fmaf(__uint_as_float(xq.z & 0xffff0000u), w1.y, contrib);
                    contrib = fmaf(__uint_as_float(xq.w << 16), w1.z, contrib);
                    contrib = fmaf(__uint_as_float(xq.w & 0xffff0000u), w1.w, contrib);
                }
                int g = v >> 2, jj = v & 3;
                #pragma unroll
                for (int t = 0; t < 4; ++t) {
                    float val = __shfl(contrib, t * 16 + c15);
                    if (g16 == g) {
                        if (jj == 0) acc[t][0] += val;
                        else if (jj == 1) acc[t][1] += val;
                        else if (jj == 2) acc[t][2] += val;
                        else acc[t][3] += val;
                    }
                }
            }
        };
        offc(m0, i0, 0);
        offc(m1, i1, 8);

        float* stg = stage[wave];
        #pragma unroll
        for (int t = 0; t < 4; ++t) {
            const int col = t * 16 + c15;
            #pragma unroll
            for (int j = 0; j < 4; ++j) {
                float v = acc[t][j];
                v = v > 0.f ? v : 0.01f * v;
                ps0[t] += v;
                ps1[t] = fmaf(v, v, ps1[t]);
                stg[(g16 * 4 + j) * 68 + col] = v;
            }
        }
        const int mm = lane >> 2, cc0 = (lane & 3) * 16;
        float4 q0 = *reinterpret_cast<float4*>(&stg[mm * 68 + cc0]);
        float4 q1 = *reinterpret_cast<float4*>(&stg[mm * 68 + cc0 + 4]);
        float4 q2 = *reinterpret_cast<float4*>(&stg[mm * 68 + cc0 + 8]);
        float4 q3 = *reinterpret_cast<float4*>(&stg[mm * 68 + cc0 + 12]);
        if constexpr (OUTF32) {
            float* yo = (float*)yout + (size_t)(v16 + mm) * 64 + cc0;
            *reinterpret_cast<float4*>(yo) = q0;
            *reinterpret_cast<float4*>(yo + 4) = q1;
            *reinterpret_cast<float4*>(yo + 8) = q2;
            *reinterpret_cast<float4*>(yo + 12) = q3;
        } else {
            uint4 o0, o1;
            o0.x = f2bf(q0.x) | ((unsigned)f2bf(q0.y) << 16);
            o0.y = f2bf(q0.z) | ((unsigned)f2bf(q0.w) << 16);
            o0.z = f2bf(q1.x) | ((unsigned)f2bf(q1.y) << 16);
            o0.w = f2bf(q1.z) | ((unsigned)f2bf(q1.w) << 16);
            o1.x = f2bf(q2.x) | ((unsigned)f2bf(q2.y) << 16);
            o1.y = f2bf(q2.z) | ((unsigned)f2bf(q2.w) << 16);
            o1.z = f2bf(q3.x) | ((unsigned)f2bf(q3.y) << 16);
            o1.w = f2bf(q3.z) | ((unsigned)f2bf(q3.w) << 16);
            uint4* dst = reinterpret_cast<uint4*>((unsigned short*)yout + (size_t)(v16 + mm) * 64 + cc0);
            dst[0] = o0; dst[1] = o1;
        }
    }

    __syncthreads();
    float* lsf = &stage[0][0];                       // reuse as [16][128]
    const int r = wave * 4 + g16;
    #pragma unroll
    for (int t = 0; t < 4; ++t) {
        lsf[r * 128 + t * 16 + c15] = ps0[t];
        lsf[r * 128 + 64 + t * 16 + c15] = ps1[t];
    }
    __syncthreads();
    const int tid = threadIdx.x;
    if (tid < 128) {
        float s = 0.f;
        #pragma unroll
        for (int rr = 0; rr < 16; ++rr) s += lsf[rr * 128 + tid];
        part[(size_t)tid * NBLK + blockIdx.x] = s;
    }
}

// ---------- reduce partials + BN scale/shift (two layers per launch) ----------
__global__ void bnred_kernel(const float* __restrict__ part,  // [2l+{0,1}][64][NBLK]
                             const float* __restrict__ gA, const float* __restrict__ bA,
                             const float* __restrict__ gB, const float* __restrict__ bB,
                             float* __restrict__ scA, float* __restrict__ shA,
                             float* __restrict__ scB, float* __restrict__ shB,
                             float invN)
{
    const int l = blockIdx.x >> 6, c = blockIdx.x & 63;   // grid 128
    const float* ps = part + ((size_t)(l * 2 + 0) * 64 + c) * NBLK;
    const float* pq = part + ((size_t)(l * 2 + 1) * 64 + c) * NBLK;
    __shared__ float red[256][2];
    float s = 0.f, q = 0.f;
    for (int b = threadIdx.x; b < NBLK; b += 256) { s += ps[b]; q += pq[b]; }
    red[threadIdx.x][0] = s; red[threadIdx.x][1] = q;
    __syncthreads();
    for (int off = 128; off; off >>= 1) {
        if (threadIdx.x < off) {
            red[threadIdx.x][0] += red[threadIdx.x + off][0];
            red[threadIdx.x][1] += red[threadIdx.x + off][1];
        }
        __syncthreads();
    }
    if (threadIdx.x == 0) {
        float m = red[0][0] * invN;
        float v = red[0][1] * invN - m * m;
        const float* g = l ? gB : gA;
        const float* bb = l ? bB : bA;
        float* sc = l ? scB : scA;
        float* sh = l ? shB : shA;
        float scale = g[c] / sqrtf(v + EPSF);
        sc[c] = scale;
        sh[c] = bb[c] - m * scale;
    }
}

// ---------- fold BN1/BN3 into W2/W4 + pack center B-frags ----------
__global__ void foldpack_kernel(const float* __restrict__ W2, const float* __restrict__ W4,
                                const float* __restrict__ sc1, const float* __restrict__ sh1,
                                const float* __restrict__ sc3, const float* __restrict__ sh3,
                                float* __restrict__ Wt2f, float* __restrict__ t2,
                                float* __restrict__ Wt4f, float* __restrict__ t4,
                                unsigned short* __restrict__ Wb2, unsigned short* __restrict__ Wb4)
{
    int i = blockIdx.x * 256 + threadIdx.x;
    if (i < 2 * 9 * 64) {
        const float* W = i < 9 * 64 ? W2 : W4;
        const float* scale = i < 9 * 64 ? sc1 : sc3;
        const float* shift = i < 9 * 64 ? sh1 : sh3;
        float* Wtf = i < 9 * 64 ? Wt2f : Wt4f;
        float* tv = i < 9 * 64 ? t2 : t4;
        int ii = i < 9 * 64 ? i : i - 9 * 64;
        int d = ii & 63, k = ii >> 6;
        float t = 0.f;
        for (int c = 0; c < 64; ++c) {
            float w = W[((size_t)k * 64 + c) * 64 + d];
            Wtf[((size_t)(k * 64 + d)) * 64 + c] = scale[c] * w;
            t = fmaf(shift[c], w, t);
        }
        tv[ii] = t;
    } else {
        int p = i - 2 * 9 * 64;
        if (p >= 2 * 4096) return;
        const float* W = p < 4096 ? W2 : W4;
        const float* scale = p < 4096 ? sc1 : sc3;
        unsigned short* Wb = p < 4096 ? Wb2 : Wb4;
        int pp = p & 4095;                 // ((kt*4+t)*64+lane)*8+j
        int j = pp & 7, lane = (pp >> 3) & 63, t = (pp >> 9) & 3, kt = pp >> 11;
        int c = kt * 32 + (lane >> 4) * 8 + j;
        int d = t * 16 + (lane & 15);
        Wb[pp] = f2bf(scale[c] * W[((size_t)4 * 64 + c) * 64 + d]);
    }
}

// ---------- final: out = BN2(y2) + BN4(y4), in-place on d_out ----------
__global__ void final_kernel(float* __restrict__ out,
                             const unsigned short* __restrict__ y4,
                             const float* __restrict__ sc2, const float* __restrict__ sh2,
                             const float* __restrict__ sc4, const float* __restrict__ sh4,
                             int n8)
{
    int i = blockIdx.x * 256 + threadIdx.x;
    if (i >= n8) return;
    const int c0 = (i & 7) * 8;
    float* po = out + (size_t)i * 8;
    float4 a0 = *reinterpret_cast<const float4*>(po);
    float4 a1 = *reinterpret_cast<const float4*>(po + 4);
    uint4 bq = *reinterpret_cast<const uint4*>(y4 + (size_t)i * 8);
    float a[8] = {a0.x, a0.y, a0.z, a0.w, a1.x, a1.y, a1.z, a1.w};
    float b[8];
    b[0] = __uint_as_float(bq.x << 16); b[1] = __uint_as_float(bq.x & 0xffff0000u);
    b[2] = __uint_as_float(bq.y << 16); b[3] = __uint_as_float(bq.y & 0xffff0000u);
    b[4] = __uint_as_float(bq.z << 16); b[5] = __uint_as_float(bq.z & 0xffff0000u);
    b[6] = __uint_as_float(bq.w << 16); b[7] = __uint_as_float(bq.w & 0xffff0000u);
    float r[8];
    #pragma unroll
    for (int j = 0; j < 8; ++j)
        r[j] = fmaf(a[j], sc2[c0 + j], sh2[c0 + j]) + fmaf(b[j], sc4[c0 + j], sh4[c0 + j]);
    float4 o0 = {r[0], r[1], r[2], r[3]};
    float4 o1 = {r[4], r[5], r[6], r[7]};
    *reinterpret_cast<float4*>(po) = o0;
    *reinterpret_cast<float4*>(po + 4) = o1;
}

extern "C" void kernel_launch(void* const* d_in, const int* in_sizes, int n_in,
                              void* d_out, int out_size, void* d_ws, size_t ws_size,
                              hipStream_t stream)
{
    const float* feats  = (const float*)d_in[0];
    const int*   nbr133 = (const int*)d_in[1];
    const int*   nbr313 = (const int*)d_in[2];
    const float* W1 = (const float*)d_in[3];
    const float* W2 = (const float*)d_in[4];
    const float* W3 = (const float*)d_in[5];
    const float* W4 = (const float*)d_in[6];
    const float* g0  = (const float*)d_in[7];
    const float* b0  = (const float*)d_in[8];
    const float* g02 = (const float*)d_in[9];
    const float* b02 = (const float*)d_in[10];
    const float* g1  = (const float*)d_in[11];
    const float* b1  = (const float*)d_in[12];
    const float* g2  = (const float*)d_in[13];
    const float* b2  = (const float*)d_in[14];

    const int N = in_sizes[0] / 32;

    char* w = (char*)d_ws;
    auto alloc = [&](size_t bytes) {
        char* p = w;
        w += (bytes + 255) & ~(size_t)255;
        return p;
    };
    unsigned short* y1 = (unsigned short*)alloc((size_t)N * 64 * 2);
    unsigned short* y3 = (unsigned short*)alloc((size_t)N * 64 * 2);
    unsigned short* y4 = (unsigned short*)alloc((size_t)N * 64 * 2);
    float* Wt1  = (float*)alloc(9 * 64 * 32 * 4);
    float* Wt3  = (float*)alloc(9 * 64 * 32 * 4);
    float* Wt2f = (float*)alloc(9 * 64 * 64 * 4);
    float* Wt4f = (float*)alloc(9 * 64 * 64 * 4);
    float* t2   = (float*)alloc(9 * 64 * 4);
    float* t4   = (float*)alloc(9 * 64 * 4);
    unsigned short* Wb1 = (unsigned short*)alloc(4 * 64 * 8 * 2);
    unsigned short* Wb3 = (unsigned short*)alloc(4 * 64 * 8 * 2);
    unsigned short* Wb2 = (unsigned short*)alloc(2 * 4 * 64 * 8 * 2);
    unsigned short* Wb4 = (unsigned short*)alloc(2 * 4 * 64 * 8 * 2);
    float* part13 = (float*)alloc((size_t)256 * NBLK * 4);
    float* part24 = (float*)alloc((size_t)256 * NBLK * 4);
    float* scl = (float*)alloc(8 * 64 * 4);
    float *sc1 = scl,       *sh1 = scl + 64;
    float *sc3 = scl + 128, *sh3 = scl + 192;
    float *sc2 = scl + 256, *sh2 = scl + 320;
    float *sc4 = scl + 384, *sh4 = scl + 448;

    const float invN = 1.0f / (float)N;

    prep_kernel<<<160, 256, 0, stream>>>(W1, W3, Wt1, Wt3, Wb1, Wb3);

    conv13_kernel<<<NBLK, 256, 0, stream>>>(feats, nbr133, nbr313, Wt1, Wt3,
                                            Wb1, Wb3, y1, y3, part13, N);
    bnred_kernel<<<128, 256, 0, stream>>>(part13, g0, b0, g1, b1,
                                          sc1, sh1, sc3, sh3, invN);
    foldpack_kernel<<<37, 256, 0, stream>>>(W2, W4, sc1, sh1, sc3, sh3,
                                            Wt2f, t2, Wt4f, t4, Wb2, Wb4);

    conv24_kernel<true><<<NBLK, 256, 0, stream>>>(y1, nbr313, Wt2f, t2, Wb2,
                                                  d_out, part24, N);
    conv24_kernel<false><<<NBLK, 256, 0, stream>>>(y3, nbr133, Wt4f, t4, Wb4,
                                                   y4, part24 + (size_t)128 * NBLK, N);
    bnred_kernel<<<128, 256, 0, stream>>>(part24, g02, b02, g2, b2,
                                          sc2, sh2, sc4, sh4, invN);

    final_kernel<<<(N * 8 + 255) / 256, 256, 0, stream>>>(
        (float*)d_out, y4, sc2, sh2, sc4, sh4, N * 8);
}

// Round 4
// 357.597 us; speedup vs baseline: 5.5248x; 1.1803x over previous
//
#include <hip/hip_runtime.h>

// ResContextBlock R4: center tap as bf16 MFMA GEMM (16x16x32), off-center rare
// taps via ballot + VALU dot + shuffle-inject into MFMA C-layout.
// R4 changes: one 64-voxel tile per block (grid=3125) for 4x occupancy;
// conv2+conv4 merged into one 6250-block dispatch; y2 stored bf16.

typedef __attribute__((ext_vector_type(8))) short bf16x8;
typedef __attribute__((ext_vector_type(4))) float f32x4;

#define EPSF 1e-5f
#define PARTN 3328   // padded partial-sum stride (>= ntile)

__device__ __forceinline__ unsigned short f2bf(float f) {
    unsigned int u = __float_as_uint(f);
    u = (u + 0x7fffu + ((u >> 16) & 1u)) >> 16;   // RNE
    return (unsigned short)u;
}
__device__ __forceinline__ float dot4(float4 a, float4 b, float acc) {
    acc = fmaf(a.x, b.x, acc);
    acc = fmaf(a.y, b.y, acc);
    acc = fmaf(a.z, b.z, acc);
    acc = fmaf(a.w, b.w, acc);
    return acc;
}

// ---------- prep: transpose W1,W3 -> Wt[9][64][32]; pack center B-frags ----------
__global__ void prep_kernel(const float* __restrict__ W1, const float* __restrict__ W3,
                            float* __restrict__ Wt1, float* __restrict__ Wt3,
                            unsigned short* __restrict__ Wb1, unsigned short* __restrict__ Wb3)
{
    int i = blockIdx.x * 256 + threadIdx.x;
    const int TT = 9 * 32 * 64;
    if (i < 2 * TT) {
        const float* W = i < TT ? W1 : W3;
        float* Wt = i < TT ? Wt1 : Wt3;
        int ii = i < TT ? i : i - TT;
        int d = ii % 64, c = (ii / 64) % 32, k = ii / (64 * 32);
        Wt[(size_t)(k * 64 + d) * 32 + c] = W[ii];
    } else {
        int p = i - 2 * TT;                 // 2 * 2048 pack jobs
        if (p >= 2 * 2048) return;
        const float* W = p < 2048 ? W1 : W3;
        unsigned short* Wb = p < 2048 ? Wb1 : Wb3;
        int pp = p & 2047;                  // ((t*64+lane)*8+j)
        int j = pp & 7, lane = (pp >> 3) & 63, t = pp >> 9;
        int c = (lane >> 4) * 8 + j;        // k (cin), kt=0
        int d = t * 16 + (lane & 15);
        Wb[pp] = f2bf(W[(size_t)(4 * 32 + c) * 64 + d]);   // center tap k=4
    }
}

// ---------- fused conv1+conv3 (CIN=32, fp32 feats in, bf16 y out) ----------
__global__ __launch_bounds__(256)
void conv13_kernel(const float* __restrict__ x,
                   const int* __restrict__ nbrA,     // 133
                   const int* __restrict__ nbrB,     // 313
                   const float* __restrict__ WtA,    // [9][64][32]
                   const float* __restrict__ WtB,
                   const unsigned short* __restrict__ WbA,
                   const unsigned short* __restrict__ WbB,
                   unsigned short* __restrict__ yA,  // bf16 [N][64]
                   unsigned short* __restrict__ yB,
                   float* __restrict__ part,         // [4*64][PARTN]
                   int n_vox)
{
    const int lane = threadIdx.x & 63;
    const int wave = threadIdx.x >> 6;
    __shared__ float stage[4][1088];                 // per-wave [16][68] + stats reuse

    const int j7 = lane & 7;
    const int kk = j7 + (j7 >= 4 ? 1 : 0);
    const int vv = lane >> 3;
    const int c15 = lane & 15;
    const int g16 = lane >> 4;

    const int tile = blockIdx.x;
    const int v16 = tile * 64 + wave * 16;

    // probes (issue first: longest chain)
    const size_t r0 = (size_t)(v16 + vv) * 9 + kk;
    const size_t r1 = (size_t)(v16 + 8 + vv) * 9 + kk;
    int iA0 = nbrA[r0], iA1 = nbrA[r1];
    int iB0 = nbrB[r0], iB1 = nbrB[r1];

    // A fragment: fp32 -> bf16
    const float* xr = x + (size_t)(v16 + c15) * 32 + (g16 * 8);
    float4 x0 = *reinterpret_cast<const float4*>(xr);
    float4 x1 = *reinterpret_cast<const float4*>(xr + 4);

    bf16x8 bA[4], bB[4];
    #pragma unroll
    for (int t = 0; t < 4; ++t) {
        bA[t] = *reinterpret_cast<const bf16x8*>(WbA + (t * 64 + lane) * 8);
        bB[t] = *reinterpret_cast<const bf16x8*>(WbB + (t * 64 + lane) * 8);
    }

    bf16x8 af;
    af[0] = (short)f2bf(x0.x); af[1] = (short)f2bf(x0.y);
    af[2] = (short)f2bf(x0.z); af[3] = (short)f2bf(x0.w);
    af[4] = (short)f2bf(x1.x); af[5] = (short)f2bf(x1.y);
    af[6] = (short)f2bf(x1.z); af[7] = (short)f2bf(x1.w);

    f32x4 accA[4], accB[4];
    #pragma unroll
    for (int t = 0; t < 4; ++t) {
        f32x4 z = {0.f, 0.f, 0.f, 0.f};
        accA[t] = z; accB[t] = z;
    }
    #pragma unroll
    for (int t = 0; t < 4; ++t) {
        accA[t] = __builtin_amdgcn_mfma_f32_16x16x32_bf16(af, bA[t], accA[t], 0, 0, 0);
        accB[t] = __builtin_amdgcn_mfma_f32_16x16x32_bf16(af, bB[t], accB[t], 0, 0, 0);
    }

    unsigned long long mA0 = __ballot(iA0 < n_vox);
    unsigned long long mA1 = __ballot(iA1 < n_vox);
    unsigned long long mB0 = __ballot(iB0 < n_vox);
    unsigned long long mB1 = __ballot(iB1 < n_vox);

    auto offc = [&](unsigned long long m, int idxv, const float* Wt, f32x4* acc, int vbase) {
        while (m) {
            int b = __builtin_ctzll(m); m &= m - 1;
            int src = __shfl(idxv, b);
            int bj = b & 7;
            int k = bj + (bj >= 4 ? 1 : 0);
            int v = vbase + (b >> 3);
            const float* wr = Wt + (size_t)(k * 64 + lane) * 32;
            const float* xs = x + (size_t)src * 32;
            float contrib = 0.f;
            #pragma unroll
            for (int c4 = 0; c4 < 8; ++c4) {
                float4 wv = *reinterpret_cast<const float4*>(wr + c4 * 4);
                float4 xv = *reinterpret_cast<const float4*>(xs + c4 * 4);
                contrib = dot4(xv, wv, contrib);
            }
            int g = v >> 2, jj = v & 3;
            #pragma unroll
            for (int t = 0; t < 4; ++t) {
                float val = __shfl(contrib, t * 16 + c15);
                if (g16 == g) {
                    if (jj == 0) acc[t][0] += val;
                    else if (jj == 1) acc[t][1] += val;
                    else if (jj == 2) acc[t][2] += val;
                    else acc[t][3] += val;
                }
            }
        }
    };
    offc(mA0, iA0, WtA, accA, 0);
    offc(mA1, iA1, WtA, accA, 8);
    offc(mB0, iB0, WtB, accB, 0);
    offc(mB1, iB1, WtB, accB, 8);

    float psA0[4], psA1[4], psB0[4], psB1[4];
    #pragma unroll
    for (int t = 0; t < 4; ++t) { psA0[t]=0.f; psA1[t]=0.f; psB0[t]=0.f; psB1[t]=0.f; }

    auto epi = [&](f32x4* acc, float* ps0, float* ps1, unsigned short* yo) {
        float* stg = stage[wave];
        #pragma unroll
        for (int t = 0; t < 4; ++t) {
            const int col = t * 16 + c15;
            #pragma unroll
            for (int j = 0; j < 4; ++j) {
                float v = acc[t][j];
                v = v > 0.f ? v : 0.01f * v;          // leaky relu
                ps0[t] += v;
                ps1[t] = fmaf(v, v, ps1[t]);
                stg[(g16 * 4 + j) * 68 + col] = v;
            }
        }
        const int mm = lane >> 2, cc0 = (lane & 3) * 16;
        float4 q0 = *reinterpret_cast<float4*>(&stg[mm * 68 + cc0]);
        float4 q1 = *reinterpret_cast<float4*>(&stg[mm * 68 + cc0 + 4]);
        float4 q2 = *reinterpret_cast<float4*>(&stg[mm * 68 + cc0 + 8]);
        float4 q3 = *reinterpret_cast<float4*>(&stg[mm * 68 + cc0 + 12]);
        uint4 o0, o1;
        o0.x = f2bf(q0.x) | ((unsigned)f2bf(q0.y) << 16);
        o0.y = f2bf(q0.z) | ((unsigned)f2bf(q0.w) << 16);
        o0.z = f2bf(q1.x) | ((unsigned)f2bf(q1.y) << 16);
        o0.w = f2bf(q1.z) | ((unsigned)f2bf(q1.w) << 16);
        o1.x = f2bf(q2.x) | ((unsigned)f2bf(q2.y) << 16);
        o1.y = f2bf(q2.z) | ((unsigned)f2bf(q2.w) << 16);
        o1.z = f2bf(q3.x) | ((unsigned)f2bf(q3.y) << 16);
        o1.w = f2bf(q3.z) | ((unsigned)f2bf(q3.w) << 16);
        uint4* dst = reinterpret_cast<uint4*>(yo + (size_t)(v16 + mm) * 64 + cc0);
        dst[0] = o0; dst[1] = o1;
    };
    epi(accA, psA0, psA1, yA);
    epi(accB, psB0, psB1, yB);

    __syncthreads();
    float* lsf = &stage[0][0];                       // reuse as [16][256]
    const int r = wave * 4 + g16;
    #pragma unroll
    for (int t = 0; t < 4; ++t) {
        lsf[r * 256 + 0 * 64 + t * 16 + c15] = psA0[t];
        lsf[r * 256 + 1 * 64 + t * 16 + c15] = psA1[t];
        lsf[r * 256 + 2 * 64 + t * 16 + c15] = psB0[t];
        lsf[r * 256 + 3 * 64 + t * 16 + c15] = psB1[t];
    }
    __syncthreads();
    const int tid = threadIdx.x;
    float s = 0.f;
    #pragma unroll
    for (int rr = 0; rr < 16; ++rr) s += lsf[rr * 256 + tid];
    part[(size_t)tid * PARTN + blockIdx.x] = s;
}

// ---------- merged conv2 & conv4 (CIN=64 bf16 in, folded W, bf16 out) ----------
__global__ __launch_bounds__(256)
void conv24_kernel(const unsigned short* __restrict__ x2,
                   const int* __restrict__ nbr2,
                   const float* __restrict__ Wt2, const float* __restrict__ tv2,
                   const unsigned short* __restrict__ Wb2,
                   unsigned short* __restrict__ y2,
                   const unsigned short* __restrict__ x4,
                   const int* __restrict__ nbr4,
                   const float* __restrict__ Wt4, const float* __restrict__ tv4,
                   const unsigned short* __restrict__ Wb4,
                   unsigned short* __restrict__ y4,
                   float* __restrict__ part,               // [256][PARTN]
                   int n_vox, int ntile)
{
    const int lane = threadIdx.x & 63;
    const int wave = threadIdx.x >> 6;
    __shared__ float stage[4][1088];

    const bool second = blockIdx.x >= ntile;
    const int tile = second ? blockIdx.x - ntile : blockIdx.x;
    const unsigned short* x = second ? x4 : x2;
    const int* nbr = second ? nbr4 : nbr2;
    const float* Wt = second ? Wt4 : Wt2;
    const float* tvec = second ? tv4 : tv2;
    const unsigned short* Wb = second ? Wb4 : Wb2;
    unsigned short* yout = second ? y4 : y2;

    const int c15 = lane & 15, g16 = lane >> 4;
    const int j7 = lane & 7;
    const int kk = j7 + (j7 >= 4 ? 1 : 0);
    const int vv = lane >> 3;

    const int v16 = tile * 64 + wave * 16;

    // probes first (longest chain)
    const size_t r0 = (size_t)(v16 + vv) * 9 + kk;
    const size_t r1 = (size_t)(v16 + 8 + vv) * 9 + kk;
    int i0 = nbr[r0], i1 = nbr[r1];

    const unsigned short* xr = x + (size_t)(v16 + c15) * 64 + g16 * 8;
    bf16x8 a0 = *reinterpret_cast<const bf16x8*>(xr);
    bf16x8 a1 = *reinterpret_cast<const bf16x8*>(xr + 32);

    bf16x8 bw[2][4];
    #pragma unroll
    for (int kt = 0; kt < 2; ++kt)
        #pragma unroll
        for (int t = 0; t < 4; ++t)
            bw[kt][t] = *reinterpret_cast<const bf16x8*>(Wb + ((kt * 4 + t) * 64 + lane) * 8);

    f32x4 acc[4];
    #pragma unroll
    for (int t = 0; t < 4; ++t) {
        float tC = tvec[4 * 64 + t * 16 + c15];
        f32x4 z = {tC, tC, tC, tC};
        acc[t] = z;
    }
    #pragma unroll
    for (int t = 0; t < 4; ++t) {
        acc[t] = __builtin_amdgcn_mfma_f32_16x16x32_bf16(a0, bw[0][t], acc[t], 0, 0, 0);
        acc[t] = __builtin_amdgcn_mfma_f32_16x16x32_bf16(a1, bw[1][t], acc[t], 0, 0, 0);
    }

    unsigned long long m0 = __ballot(i0 < n_vox);
    unsigned long long m1 = __ballot(i1 < n_vox);

    auto offc = [&](unsigned long long m, int idxv, int vbase) {
        while (m) {
            int b = __builtin_ctzll(m); m &= m - 1;
            int src = __shfl(idxv, b);
            int bj = b & 7;
            int k = bj + (bj >= 4 ? 1 : 0);
            int v = vbase + (b >> 3);
            const float* wr = Wt + (size_t)(k * 64 + lane) * 64;
            const unsigned short* xs = x + (size_t)src * 64;
            float contrib = tvec[k * 64 + lane];
            #pragma unroll
            for (int q = 0; q < 8; ++q) {
                uint4 xq = *reinterpret_cast<const uint4*>(xs + q * 8);
                float4 w0 = *reinterpret_cast<const float4*>(wr + q * 8);
                float4 w1 = *reinterpret_cast<const float4*>(wr + q * 8 + 4);
                contrib = fmaf(__uint_as_float(xq.x << 16), w0.x, contrib);
                contrib = fmaf(__uint_as_float(xq.x & 0xffff0000u), w0.y, contrib);
                contrib = fmaf(__uint_as_float(xq.y << 16), w0.z, contrib);
                contrib = fmaf(__uint_as_float(xq.y & 0xffff0000u), w0.w, contrib);
                contrib = fmaf(__uint_as_float(xq.z << 16), w1.x, contrib);
                contrib = fmaf(__uint_as_float(xq.z & 0xffff0000u), w1.y, contrib);
                contrib = fmaf(__uint_as_float(xq.w << 16), w1.z, contrib);
                contrib = fmaf(__uint_as_float(xq.w & 0xffff0000u), w1.w, contrib);
            }
            int g = v >> 2, jj = v & 3;
            #pragma unroll
            for (int t = 0; t < 4; ++t) {
                float val = __shfl(contrib, t * 16 + c15);
                if (g16 == g) {
                    if (jj == 0) acc[t][0] += val;
                    else if (jj == 1) acc[t][1] += val;
                    else if (jj == 2) acc[t][2] += val;
                    else acc[t][3] += val;
                }
            }
        }
    };
    offc(m0, i0, 0);
    offc(m1, i1, 8);

    float ps0[4] = {0,0,0,0}, ps1[4] = {0,0,0,0};
    float* stg = stage[wave];
    #pragma unroll
    for (int t = 0; t < 4; ++t) {
        const int col = t * 16 + c15;
        #pragma unroll
        for (int j = 0; j < 4; ++j) {
            float v = acc[t][j];
            v = v > 0.f ? v : 0.01f * v;
            ps0[t] += v;
            ps1[t] = fmaf(v, v, ps1[t]);
            stg[(g16 * 4 + j) * 68 + col] = v;
        }
    }
    const int mm = lane >> 2, cc0 = (lane & 3) * 16;
    float4 q0 = *reinterpret_cast<float4*>(&stg[mm * 68 + cc0]);
    float4 q1 = *reinterpret_cast<float4*>(&stg[mm * 68 + cc0 + 4]);
    float4 q2 = *reinterpret_cast<float4*>(&stg[mm * 68 + cc0 + 8]);
    float4 q3 = *reinterpret_cast<float4*>(&stg[mm * 68 + cc0 + 12]);
    uint4 o0, o1;
    o0.x = f2bf(q0.x) | ((unsigned)f2bf(q0.y) << 16);
    o0.y = f2bf(q0.z) | ((unsigned)f2bf(q0.w) << 16);
    o0.z = f2bf(q1.x) | ((unsigned)f2bf(q1.y) << 16);
    o0.w = f2bf(q1.z) | ((unsigned)f2bf(q1.w) << 16);
    o1.x = f2bf(q2.x) | ((unsigned)f2bf(q2.y) << 16);
    o1.y = f2bf(q2.z) | ((unsigned)f2bf(q2.w) << 16);
    o1.z = f2bf(q3.x) | ((unsigned)f2bf(q3.y) << 16);
    o1.w = f2bf(q3.z) | ((unsigned)f2bf(q3.w) << 16);
    uint4* dst = reinterpret_cast<uint4*>(yout + (size_t)(v16 + mm) * 64 + cc0);
    dst[0] = o0; dst[1] = o1;

    __syncthreads();
    float* lsf = &stage[0][0];                       // reuse as [16][128]
    const int r = wave * 4 + g16;
    #pragma unroll
    for (int t = 0; t < 4; ++t) {
        lsf[r * 128 + t * 16 + c15] = ps0[t];
        lsf[r * 128 + 64 + t * 16 + c15] = ps1[t];
    }
    __syncthreads();
    const int tid = threadIdx.x;
    if (tid < 128) {
        float s = 0.f;
        #pragma unroll
        for (int rr = 0; rr < 16; ++rr) s += lsf[rr * 128 + tid];
        part[((size_t)(second ? 128 : 0) + tid) * PARTN + tile] = s;
    }
}

// ---------- reduce partials + BN scale/shift (two layers per launch) ----------
__global__ void bnred_kernel(const float* __restrict__ part,  // [2l+{0,1}][64][PARTN]
                             const float* __restrict__ gA, const float* __restrict__ bA,
                             const float* __restrict__ gB, const float* __restrict__ bB,
                             float* __restrict__ scA, float* __restrict__ shA,
                             float* __restrict__ scB, float* __restrict__ shB,
                             float invN, int nblk)
{
    const int l = blockIdx.x >> 6, c = blockIdx.x & 63;   // grid 128
    const float* ps = part + ((size_t)(l * 2 + 0) * 64 + c) * PARTN;
    const float* pq = part + ((size_t)(l * 2 + 1) * 64 + c) * PARTN;
    __shared__ float red[256][2];
    float s = 0.f, q = 0.f;
    for (int b = threadIdx.x; b < nblk; b += 256) { s += ps[b]; q += pq[b]; }
    red[threadIdx.x][0] = s; red[threadIdx.x][1] = q;
    __syncthreads();
    for (int off = 128; off; off >>= 1) {
        if (threadIdx.x < off) {
            red[threadIdx.x][0] += red[threadIdx.x + off][0];
            red[threadIdx.x][1] += red[threadIdx.x + off][1];
        }
        __syncthreads();
    }
    if (threadIdx.x == 0) {
        float m = red[0][0] * invN;
        float v = red[0][1] * invN - m * m;
        const float* g = l ? gB : gA;
        const float* bb = l ? bB : bA;
        float* sc = l ? scB : scA;
        float* sh = l ? shB : shA;
        float scale = g[c] / sqrtf(v + EPSF);
        sc[c] = scale;
        sh[c] = bb[c] - m * scale;
    }
}

// ---------- fold BN1/BN3 into W2/W4 + pack center B-frags ----------
__global__ void foldpack_kernel(const float* __restrict__ W2, const float* __restrict__ W4,
                                const float* __restrict__ sc1, const float* __restrict__ sh1,
                                const float* __restrict__ sc3, const float* __restrict__ sh3,
                                float* __restrict__ Wt2f, float* __restrict__ t2,
                                float* __restrict__ Wt4f, float* __restrict__ t4,
                                unsigned short* __restrict__ Wb2, unsigned short* __restrict__ Wb4)
{
    int i = blockIdx.x * 256 + threadIdx.x;
    if (i < 2 * 9 * 64) {
        const float* W = i < 9 * 64 ? W2 : W4;
        const float* scale = i < 9 * 64 ? sc1 : sc3;
        const float* shift = i < 9 * 64 ? sh1 : sh3;
        float* Wtf = i < 9 * 64 ? Wt2f : Wt4f;
        float* tv = i < 9 * 64 ? t2 : t4;
        int ii = i < 9 * 64 ? i : i - 9 * 64;
        int d = ii & 63, k = ii >> 6;
        float t = 0.f;
        for (int c = 0; c < 64; ++c) {
            float w = W[((size_t)k * 64 + c) * 64 + d];
            Wtf[((size_t)(k * 64 + d)) * 64 + c] = scale[c] * w;
            t = fmaf(shift[c], w, t);
        }
        tv[ii] = t;
    } else {
        int p = i - 2 * 9 * 64;
        if (p >= 2 * 4096) return;
        const float* W = p < 4096 ? W2 : W4;
        const float* scale = p < 4096 ? sc1 : sc3;
        unsigned short* Wb = p < 4096 ? Wb2 : Wb4;
        int pp = p & 4095;                 // ((kt*4+t)*64+lane)*8+j
        int j = pp & 7, lane = (pp >> 3) & 63, t = (pp >> 9) & 3, kt = pp >> 11;
        int c = kt * 32 + (lane >> 4) * 8 + j;
        int d = t * 16 + (lane & 15);
        Wb[pp] = f2bf(scale[c] * W[((size_t)4 * 64 + c) * 64 + d]);
    }
}

// ---------- final: out = BN2(y2) + BN4(y4), both bf16 in, fp32 out ----------
__global__ void final_kernel(const unsigned short* __restrict__ y2,
                             const unsigned short* __restrict__ y4,
                             const float* __restrict__ sc2, const float* __restrict__ sh2,
                             const float* __restrict__ sc4, const float* __restrict__ sh4,
                             float* __restrict__ out, int n8)
{
    int i = blockIdx.x * 256 + threadIdx.x;
    if (i >= n8) return;
    const int c0 = (i & 7) * 8;
    uint4 aq = *reinterpret_cast<const uint4*>(y2 + (size_t)i * 8);
    uint4 bq = *reinterpret_cast<const uint4*>(y4 + (size_t)i * 8);
    float a[8], b[8];
    a[0] = __uint_as_float(aq.x << 16); a[1] = __uint_as_float(aq.x & 0xffff0000u);
    a[2] = __uint_as_float(aq.y << 16); a[3] = __uint_as_float(aq.y & 0xffff0000u);
    a[4] = __uint_as_float(aq.z << 16); a[5] = __uint_as_float(aq.z & 0xffff0000u);
    a[6] = __uint_as_float(aq.w << 16); a[7] = __uint_as_float(aq.w & 0xffff0000u);
    b[0] = __uint_as_float(bq.x << 16); b[1] = __uint_as_float(bq.x & 0xffff0000u);
    b[2] = __uint_as_float(bq.y << 16); b[3] = __uint_as_float(bq.y & 0xffff0000u);
    b[4] = __uint_as_float(bq.z << 16); b[5] = __uint_as_float(bq.z & 0xffff0000u);
    b[6] = __uint_as_float(bq.w << 16); b[7] = __uint_as_float(bq.w & 0xffff0000u);
    float r[8];
    #pragma unroll
    for (int j = 0; j < 8; ++j)
        r[j] = fmaf(a[j], sc2[c0 + j], sh2[c0 + j]) + fmaf(b[j], sc4[c0 + j], sh4[c0 + j]);
    float4 o0 = {r[0], r[1], r[2], r[3]};
    float4 o1 = {r[4], r[5], r[6], r[7]};
    float* po = out + (size_t)i * 8;
    *reinterpret_cast<float4*>(po) = o0;
    *reinterpret_cast<float4*>(po + 4) = o1;
}

extern "C" void kernel_launch(void* const* d_in, const int* in_sizes, int n_in,
                              void* d_out, int out_size, void* d_ws, size_t ws_size,
                              hipStream_t stream)
{
    const float* feats  = (const float*)d_in[0];
    const int*   nbr133 = (const int*)d_in[1];
    const int*   nbr313 = (const int*)d_in[2];
    const float* W1 = (const float*)d_in[3];
    const float* W2 = (const float*)d_in[4];
    const float* W3 = (const float*)d_in[5];
    const float* W4 = (const float*)d_in[6];
    const float* g0  = (const float*)d_in[7];
    const float* b0  = (const float*)d_in[8];
    const float* g02 = (const float*)d_in[9];
    const float* b02 = (const float*)d_in[10];
    const float* g1  = (const float*)d_in[11];
    const float* b1  = (const float*)d_in[12];
    const float* g2  = (const float*)d_in[13];
    const float* b2  = (const float*)d_in[14];

    const int N = in_sizes[0] / 32;
    const int ntile = N >> 6;                         // 3125 for N=200000

    char* w = (char*)d_ws;
    auto alloc = [&](size_t bytes) {
        char* p = w;
        w += (bytes + 255) & ~(size_t)255;
        return p;
    };
    unsigned short* y1 = (unsigned short*)alloc((size_t)N * 64 * 2);
    unsigned short* y3 = (unsigned short*)alloc((size_t)N * 64 * 2);
    unsigned short* y2 = (unsigned short*)alloc((size_t)N * 64 * 2);
    unsigned short* y4 = (unsigned short*)alloc((size_t)N * 64 * 2);
    float* Wt1  = (float*)alloc(9 * 64 * 32 * 4);
    float* Wt3  = (float*)alloc(9 * 64 * 32 * 4);
    float* Wt2f = (float*)alloc(9 * 64 * 64 * 4);
    float* Wt4f = (float*)alloc(9 * 64 * 64 * 4);
    float* t2   = (float*)alloc(9 * 64 * 4);
    float* t4   = (float*)alloc(9 * 64 * 4);
    unsigned short* Wb1 = (unsigned short*)alloc(4 * 64 * 8 * 2);
    unsigned short* Wb3 = (unsigned short*)alloc(4 * 64 * 8 * 2);
    unsigned short* Wb2 = (unsigned short*)alloc(2 * 4 * 64 * 8 * 2);
    unsigned short* Wb4 = (unsigned short*)alloc(2 * 4 * 64 * 8 * 2);
    float* part13 = (float*)alloc((size_t)256 * PARTN * 4);
    float* part24 = (float*)alloc((size_t)256 * PARTN * 4);
    float* scl = (float*)alloc(8 * 64 * 4);
    float *sc1 = scl,       *sh1 = scl + 64;
    float *sc3 = scl + 128, *sh3 = scl + 192;
    float *sc2 = scl + 256, *sh2 = scl + 320;
    float *sc4 = scl + 384, *sh4 = scl + 448;

    const float invN = 1.0f / (float)N;

    prep_kernel<<<160, 256, 0, stream>>>(W1, W3, Wt1, Wt3, Wb1, Wb3);

    conv13_kernel<<<ntile, 256, 0, stream>>>(feats, nbr133, nbr313, Wt1, Wt3,
                                             Wb1, Wb3, y1, y3, part13, N);
    bnred_kernel<<<128, 256, 0, stream>>>(part13, g0, b0, g1, b1,
                                          sc1, sh1, sc3, sh3, invN, ntile);
    foldpack_kernel<<<37, 256, 0, stream>>>(W2, W4, sc1, sh1, sc3, sh3,
                                            Wt2f, t2, Wt4f, t4, Wb2, Wb4);

    conv24_kernel<<<2 * ntile, 256, 0, stream>>>(y1, nbr313, Wt2f, t2, Wb2, y2,
                                                 y3, nbr133, Wt4f, t4, Wb4, y4,
                                                 part24, N, ntile);
    bnred_kernel<<<128, 256, 0, stream>>>(part24, g02, b02, g2, b2,
                                          sc2, sh2, sc4, sh4, invN, ntile);

    final_kernel<<<(N * 8 + 255) / 256, 256, 0, stream>>>(
        y2, y4, sc2, sh2, sc4, sh4, (float*)d_out, N * 8);
}

// Round 5
// 148.769 us; speedup vs baseline: 13.2799x; 2.4037x over previous
//
#include <hip/hip_runtime.h>

// ResContextBlock R5: dense center tap via bf16 MFMA (as R4) + off-center hits
// batched through MFMA: stage hit rows to LDS (2 loads), one A-frag for all
// hits, per-present-k B-frag + MFMA, shuffle-inject into dense acc.
// Partials transposed to [tile][256] (contiguous block writes).

typedef __attribute__((ext_vector_type(8))) short bf16x8;
typedef __attribute__((ext_vector_type(4))) float f32x4;
typedef unsigned long long ull;

#define EPSF 1e-5f
#define REP8 0x0101010101010101ull

__device__ __forceinline__ unsigned short f2bf(float f) {
    unsigned int u = __float_as_uint(f);
    u = (u + 0x7fffu + ((u >> 16) & 1u)) >> 16;   // RNE
    return (unsigned short)u;
}

// ---------- prep: pack W1,W3 -> bf16 B-frags for ALL 9 ks ----------
// Wb[((k*4+t)*64+lane)*8+j] = W[k][c=(lane>>4)*8+j][d=t*16+(lane&15)]
__global__ void prep_kernel(const float* __restrict__ W1, const float* __restrict__ W3,
                            unsigned short* __restrict__ Wb1, unsigned short* __restrict__ Wb3)
{
    int i = blockIdx.x * 256 + threadIdx.x;
    if (i >= 2 * 9 * 2048) return;
    const float* W = i < 9 * 2048 ? W1 : W3;
    unsigned short* Wb = i < 9 * 2048 ? Wb1 : Wb3;
    int pp = i < 9 * 2048 ? i : i - 9 * 2048;
    int k = pp >> 11, rest = pp & 2047;
    int t = (rest >> 9) & 3, lane = (rest >> 3) & 63, j = rest & 7;
    int c = (lane >> 4) * 8 + j;
    int d = t * 16 + (lane & 15);
    Wb[pp] = f2bf(W[(size_t)(k * 32 + c) * 64 + d]);
}

// ---------- fused conv1+conv3 (CIN=32 fp32 in, bf16 y out) ----------
__global__ __launch_bounds__(256)
void conv13_kernel(const float* __restrict__ x,
                   const int* __restrict__ nbrA, const int* __restrict__ nbrB,
                   const unsigned short* __restrict__ WbA,
                   const unsigned short* __restrict__ WbB,
                   unsigned short* __restrict__ yA, unsigned short* __restrict__ yB,
                   float* __restrict__ part,    // [tile][256]
                   int n_vox)
{
    const int lane = threadIdx.x & 63;
    const int wave = threadIdx.x >> 6;
    __shared__ float stage[4][1088];
    __shared__ uint4 hitbuf[4][256];            // per wave: A rows @0, B rows @2048B
    const int c15 = lane & 15, g16 = lane >> 4;
    const int j7 = lane & 7, kk = j7 + (j7 >= 4 ? 1 : 0), vv = lane >> 3;
    const int v16 = blockIdx.x * 64 + wave * 16;

    // probes
    const size_t r0 = (size_t)(v16 + vv) * 9 + kk;
    const size_t r1 = (size_t)(v16 + 8 + vv) * 9 + kk;
    int pA0 = nbrA[r0], pA1 = nbrA[r1];
    int pB0 = nbrB[r0], pB1 = nbrB[r1];

    // dense A-frag (fp32 -> bf16)
    const float* xr = x + (size_t)(v16 + c15) * 32 + g16 * 8;
    float4 x0 = *reinterpret_cast<const float4*>(xr);
    float4 x1 = *reinterpret_cast<const float4*>(xr + 4);

    bf16x8 bA[4], bB[4];
    #pragma unroll
    for (int t = 0; t < 4; ++t) {
        bA[t] = *reinterpret_cast<const bf16x8*>(WbA + (size_t)((4*4+t)*64 + lane) * 8);
        bB[t] = *reinterpret_cast<const bf16x8*>(WbB + (size_t)((4*4+t)*64 + lane) * 8);
    }
    bf16x8 af;
    af[0]=(short)f2bf(x0.x); af[1]=(short)f2bf(x0.y); af[2]=(short)f2bf(x0.z); af[3]=(short)f2bf(x0.w);
    af[4]=(short)f2bf(x1.x); af[5]=(short)f2bf(x1.y); af[6]=(short)f2bf(x1.z); af[7]=(short)f2bf(x1.w);

    f32x4 accA[4], accB[4];
    #pragma unroll
    for (int t = 0; t < 4; ++t) { f32x4 z = {0.f,0.f,0.f,0.f}; accA[t] = z; accB[t] = z; }
    #pragma unroll
    for (int t = 0; t < 4; ++t) {
        accA[t] = __builtin_amdgcn_mfma_f32_16x16x32_bf16(af, bA[t], accA[t], 0, 0, 0);
        accB[t] = __builtin_amdgcn_mfma_f32_16x16x32_bf16(af, bB[t], accB[t], 0, 0, 0);
    }

    ull mA0 = __ballot(pA0 < n_vox), mA1 = __ballot(pA1 < n_vox);
    ull mB0 = __ballot(pB0 < n_vox), mB1 = __ballot(pB1 < n_vox);
    const int nhA = __popcll(mA0) + __popcll(mA1);
    const int nhB = __popcll(mB0) + __popcll(mB1);

    char* hb = (char*)&hitbuf[wave][0];

    // walk mask, select src for slots [base, base+16): sel0 rows 0-7, sel1 rows 8-15
    auto walksel = [&](ull M, int preg, int slot, int base, int& sel0, int& sel1) {
        while (M) {
            int b = __builtin_ctzll(M); M &= M - 1;
            int src = __shfl(preg, b);
            int rs = slot - base;
            sel0 = ((lane >> 3) == rs)     ? src : sel0;
            sel1 = ((lane >> 3) == rs - 8) ? src : sel1;
            ++slot;
        }
        return slot;
    };
    // stage 16 rows x 128B
    auto stage2 = [&](int s0, int s1, int off4) {
        uint4 q0 = *reinterpret_cast<const uint4*>((const char*)x + (size_t)s0*128 + (lane&7)*16);
        uint4 q1 = *reinterpret_cast<const uint4*>((const char*)x + (size_t)s1*128 + (lane&7)*16);
        reinterpret_cast<uint4*>(hb)[off4 + lane]      = q0;
        reinterpret_cast<uint4*>(hb)[off4 + 64 + lane] = q1;
    };
    // A-frag from staged fp32 rows
    auto loadfrag = [&](int hbyte) {
        const float* hf = reinterpret_cast<const float*>(hb + hbyte + c15 * 128 + g16 * 32);
        float4 f0 = *reinterpret_cast<const float4*>(hf);
        float4 f1 = *reinterpret_cast<const float4*>(hf + 4);
        bf16x8 h;
        h[0]=(short)f2bf(f0.x); h[1]=(short)f2bf(f0.y); h[2]=(short)f2bf(f0.z); h[3]=(short)f2bf(f0.w);
        h[4]=(short)f2bf(f1.x); h[5]=(short)f2bf(f1.y); h[6]=(short)f2bf(f1.z); h[7]=(short)f2bf(f1.w);
        return h;
    };
    // per-present-k MFMA batch + shuffle-inject
    auto kloop = [&](ull m0, ull m1, bf16x8 h, const unsigned short* Wb,
                     f32x4* acc, int base) {
        const int pref = __popcll(m0);
        for (int tap = 0; tap < 8; ++tap) {
            ull TM = REP8 << tap;
            ull k0 = m0 & TM, k1 = m1 & TM;
            if (!(k0 | k1)) continue;
            int k = tap + (tap >= 4 ? 1 : 0);
            bf16x8 bk[4];
            #pragma unroll
            for (int t = 0; t < 4; ++t)
                bk[t] = *reinterpret_cast<const bf16x8*>(Wb + (size_t)((k*4+t)*64 + lane) * 8);
            f32x4 ch[4];
            #pragma unroll
            for (int t = 0; t < 4; ++t) { f32x4 z = {0.f,0.f,0.f,0.f}; ch[t] = z; }
            #pragma unroll
            for (int t = 0; t < 4; ++t)
                ch[t] = __builtin_amdgcn_mfma_f32_16x16x32_bf16(h, bk[t], ch[t], 0, 0, 0);
            auto inj = [&](ull M, ull msrc, int spref, int vbase) {
                while (M) {
                    int b = __builtin_ctzll(M); M &= M - 1;
                    int slot = spref + __popcll(msrc & ((1ull << b) - 1ull));
                    int rs = slot - base;
                    if (rs < 0 || rs >= 16) continue;
                    int vb = vbase + (b >> 3);
                    int g = rs >> 2, jj = rs & 3, gp = vb >> 2, jp = vb & 3;
                    #pragma unroll
                    for (int t = 0; t < 4; ++t) {
                        float v = __shfl(jj==0?ch[t][0]:jj==1?ch[t][1]:jj==2?ch[t][2]:ch[t][3],
                                         g * 16 + c15);
                        bool mine = (g16 == gp);
                        acc[t][0] += (mine && jp==0) ? v : 0.f;
                        acc[t][1] += (mine && jp==1) ? v : 0.f;
                        acc[t][2] += (mine && jp==2) ? v : 0.f;
                        acc[t][3] += (mine && jp==3) ? v : 0.f;
                    }
                }
            };
            inj(k0, m0, 0, 0);
            inj(k1, m1, pref, 8);
        }
    };

    // batch-0 staging for BOTH tables (overlapped loads)
    {
        int sA0=0, sA1=0, sB0=0, sB1=0;
        int cA = walksel(mA0, pA0, 0, 0, sA0, sA1);
        walksel(mA1, pA1, cA, 0, sA0, sA1);
        int cB = walksel(mB0, pB0, 0, 0, sB0, sB1);
        walksel(mB1, pB1, cB, 0, sB0, sB1);
        stage2(sA0, sA1, 0);
        stage2(sB0, sB1, 128);
    }
    if (nhA) {
        bf16x8 hA = loadfrag(0);
        kloop(mA0, mA1, hA, WbA, accA, 0);
        for (int base = 16; base < nhA; base += 16) {
            int s0=0, s1=0;
            int c0 = walksel(mA0, pA0, 0, base, s0, s1);
            walksel(mA1, pA1, c0, base, s0, s1);
            stage2(s0, s1, 0);
            bf16x8 h = loadfrag(0);
            kloop(mA0, mA1, h, WbA, accA, base);
        }
    }
    if (nhB) {
        bf16x8 hB = loadfrag(2048);
        kloop(mB0, mB1, hB, WbB, accB, 0);
        for (int base = 16; base < nhB; base += 16) {
            int s0=0, s1=0;
            int c0 = walksel(mB0, pB0, 0, base, s0, s1);
            walksel(mB1, pB1, c0, base, s0, s1);
            stage2(s0, s1, 128);
            bf16x8 h = loadfrag(2048);
            kloop(mB0, mB1, h, WbB, accB, base);
        }
    }

    // epilogue: lrelu, stats, pack bf16, store
    float psA0[4], psA1[4], psB0[4], psB1[4];
    #pragma unroll
    for (int t = 0; t < 4; ++t) { psA0[t]=0.f; psA1[t]=0.f; psB0[t]=0.f; psB1[t]=0.f; }

    auto epi = [&](f32x4* acc, float* ps0, float* ps1, unsigned short* yo) {
        float* stg = stage[wave];
        #pragma unroll
        for (int t = 0; t < 4; ++t) {
            const int col = t * 16 + c15;
            #pragma unroll
            for (int j = 0; j < 4; ++j) {
                float v = acc[t][j];
                v = v > 0.f ? v : 0.01f * v;
                ps0[t] += v;
                ps1[t] = fmaf(v, v, ps1[t]);
                stg[(g16 * 4 + j) * 68 + col] = v;
            }
        }
        const int mm = lane >> 2, cc0 = (lane & 3) * 16;
        float4 q0 = *reinterpret_cast<float4*>(&stg[mm * 68 + cc0]);
        float4 q1 = *reinterpret_cast<float4*>(&stg[mm * 68 + cc0 + 4]);
        float4 q2 = *reinterpret_cast<float4*>(&stg[mm * 68 + cc0 + 8]);
        float4 q3 = *reinterpret_cast<float4*>(&stg[mm * 68 + cc0 + 12]);
        uint4 o0, o1;
        o0.x = f2bf(q0.x) | ((unsigned)f2bf(q0.y) << 16);
        o0.y = f2bf(q0.z) | ((unsigned)f2bf(q0.w) << 16);
        o0.z = f2bf(q1.x) | ((unsigned)f2bf(q1.y) << 16);
        o0.w = f2bf(q1.z) | ((unsigned)f2bf(q1.w) << 16);
        o1.x = f2bf(q2.x) | ((unsigned)f2bf(q2.y) << 16);
        o1.y = f2bf(q2.z) | ((unsigned)f2bf(q2.w) << 16);
        o1.z = f2bf(q3.x) | ((unsigned)f2bf(q3.y) << 16);
        o1.w = f2bf(q3.z) | ((unsigned)f2bf(q3.w) << 16);
        uint4* dst = reinterpret_cast<uint4*>(yo + (size_t)(v16 + mm) * 64 + cc0);
        dst[0] = o0; dst[1] = o1;
    };
    epi(accA, psA0, psA1, yA);
    epi(accB, psB0, psB1, yB);

    __syncthreads();
    float* lsf = &stage[0][0];                       // reuse as [16][256]
    const int r = wave * 4 + g16;
    #pragma unroll
    for (int t = 0; t < 4; ++t) {
        lsf[r * 256 + 0 * 64 + t * 16 + c15] = psA0[t];
        lsf[r * 256 + 1 * 64 + t * 16 + c15] = psA1[t];
        lsf[r * 256 + 2 * 64 + t * 16 + c15] = psB0[t];
        lsf[r * 256 + 3 * 64 + t * 16 + c15] = psB1[t];
    }
    __syncthreads();
    const int tid = threadIdx.x;
    float s = 0.f;
    #pragma unroll
    for (int rr = 0; rr < 16; ++rr) s += lsf[rr * 256 + tid];
    part[(size_t)blockIdx.x * 256 + tid] = s;
}

// ---------- merged conv2 & conv4 (CIN=64 bf16, folded W, bf16 out) ----------
__global__ __launch_bounds__(256)
void conv24_kernel(const unsigned short* __restrict__ x2, const int* __restrict__ nbr2,
                   const float* __restrict__ tv2, const unsigned short* __restrict__ Wb2,
                   unsigned short* __restrict__ y2,
                   const unsigned short* __restrict__ x4, const int* __restrict__ nbr4,
                   const float* __restrict__ tv4, const unsigned short* __restrict__ Wb4,
                   unsigned short* __restrict__ y4,
                   float* __restrict__ part,    // [tile][256]
                   int n_vox, int ntile)
{
    const int lane = threadIdx.x & 63;
    const int wave = threadIdx.x >> 6;
    __shared__ float stage[4][1088];
    __shared__ uint4 hitbuf[4][128];             // 2KB/wave
    const bool second = blockIdx.x >= ntile;
    const int tile = second ? blockIdx.x - ntile : blockIdx.x;
    const unsigned short* x = second ? x4 : x2;
    const int* nbr = second ? nbr4 : nbr2;
    const float* tvec = second ? tv4 : tv2;
    const unsigned short* Wb = second ? Wb4 : Wb2;
    unsigned short* yout = second ? y4 : y2;

    const int c15 = lane & 15, g16 = lane >> 4;
    const int j7 = lane & 7, kk = j7 + (j7 >= 4 ? 1 : 0), vv = lane >> 3;
    const int v16 = tile * 64 + wave * 16;

    const size_t r0 = (size_t)(v16 + vv) * 9 + kk;
    const size_t r1 = (size_t)(v16 + 8 + vv) * 9 + kk;
    int p0 = nbr[r0], p1 = nbr[r1];

    const unsigned short* xr = x + (size_t)(v16 + c15) * 64 + g16 * 8;
    bf16x8 a0 = *reinterpret_cast<const bf16x8*>(xr);
    bf16x8 a1 = *reinterpret_cast<const bf16x8*>(xr + 32);

    bf16x8 bwC[2][4];
    #pragma unroll
    for (int kt = 0; kt < 2; ++kt)
        #pragma unroll
        for (int t = 0; t < 4; ++t)
            bwC[kt][t] = *reinterpret_cast<const bf16x8*>(Wb + (size_t)(((4*2+kt)*4+t)*64 + lane) * 8);

    f32x4 acc[4];
    #pragma unroll
    for (int t = 0; t < 4; ++t) {
        float tC = tvec[4 * 64 + t * 16 + c15];
        f32x4 z = {tC, tC, tC, tC};
        acc[t] = z;
    }
    #pragma unroll
    for (int t = 0; t < 4; ++t) {
        acc[t] = __builtin_amdgcn_mfma_f32_16x16x32_bf16(a0, bwC[0][t], acc[t], 0, 0, 0);
        acc[t] = __builtin_amdgcn_mfma_f32_16x16x32_bf16(a1, bwC[1][t], acc[t], 0, 0, 0);
    }

    ull m0 = __ballot(p0 < n_vox), m1 = __ballot(p1 < n_vox);
    const int nh = __popcll(m0) + __popcll(m1);

    char* hb = (char*)&hitbuf[wave][0];

    auto walksel = [&](ull M, int preg, int slot, int base, int& sel0, int& sel1) {
        while (M) {
            int b = __builtin_ctzll(M); M &= M - 1;
            int src = __shfl(preg, b);
            int rs = slot - base;
            sel0 = ((lane >> 3) == rs)     ? src : sel0;
            sel1 = ((lane >> 3) == rs - 8) ? src : sel1;
            ++slot;
        }
        return slot;
    };
    auto stage2 = [&](int s0, int s1) {
        uint4 q0 = *reinterpret_cast<const uint4*>((const char*)x + (size_t)s0*128 + (lane&7)*16);
        uint4 q1 = *reinterpret_cast<const uint4*>((const char*)x + (size_t)s1*128 + (lane&7)*16);
        reinterpret_cast<uint4*>(hb)[lane]      = q0;
        reinterpret_cast<uint4*>(hb)[64 + lane] = q1;
    };
    auto kloop = [&](bf16x8 h0, bf16x8 h1, int base) {
        const int pref = __popcll(m0);
        for (int tap = 0; tap < 8; ++tap) {
            ull TM = REP8 << tap;
            ull k0 = m0 & TM, k1 = m1 & TM;
            if (!(k0 | k1)) continue;
            int k = tap + (tap >= 4 ? 1 : 0);
            bf16x8 bk[2][4];
            #pragma unroll
            for (int kt = 0; kt < 2; ++kt)
                #pragma unroll
                for (int t = 0; t < 4; ++t)
                    bk[kt][t] = *reinterpret_cast<const bf16x8*>(Wb + (size_t)(((k*2+kt)*4+t)*64 + lane) * 8);
            float tvk[4];
            #pragma unroll
            for (int t = 0; t < 4; ++t) tvk[t] = tvec[k * 64 + t * 16 + c15];
            f32x4 ch[4];
            #pragma unroll
            for (int t = 0; t < 4; ++t) { f32x4 z = {0.f,0.f,0.f,0.f}; ch[t] = z; }
            #pragma unroll
            for (int t = 0; t < 4; ++t) {
                ch[t] = __builtin_amdgcn_mfma_f32_16x16x32_bf16(h0, bk[0][t], ch[t], 0, 0, 0);
                ch[t] = __builtin_amdgcn_mfma_f32_16x16x32_bf16(h1, bk[1][t], ch[t], 0, 0, 0);
            }
            auto inj = [&](ull M, ull msrc, int spref, int vbase) {
                while (M) {
                    int b = __builtin_ctzll(M); M &= M - 1;
                    int slot = spref + __popcll(msrc & ((1ull << b) - 1ull));
                    int rs = slot - base;
                    if (rs < 0 || rs >= 16) continue;
                    int vb = vbase + (b >> 3);
                    int g = rs >> 2, jj = rs & 3, gp = vb >> 2, jp = vb & 3;
                    #pragma unroll
                    for (int t = 0; t < 4; ++t) {
                        float v = __shfl(jj==0?ch[t][0]:jj==1?ch[t][1]:jj==2?ch[t][2]:ch[t][3],
                                         g * 16 + c15);
                        v += tvk[t];
                        bool mine = (g16 == gp);
                        acc[t][0] += (mine && jp==0) ? v : 0.f;
                        acc[t][1] += (mine && jp==1) ? v : 0.f;
                        acc[t][2] += (mine && jp==2) ? v : 0.f;
                        acc[t][3] += (mine && jp==3) ? v : 0.f;
                    }
                }
            };
            inj(k0, m0, 0, 0);
            inj(k1, m1, pref, 8);
        }
    };

    {
        int s0 = 0, s1 = 0;
        int c0 = walksel(m0, p0, 0, 0, s0, s1);
        walksel(m1, p1, c0, 0, s0, s1);
        stage2(s0, s1);
    }
    if (nh) {
        bf16x8 h0 = *reinterpret_cast<const bf16x8*>(hb + c15 * 128 + g16 * 16);
        bf16x8 h1 = *reinterpret_cast<const bf16x8*>(hb + c15 * 128 + 64 + g16 * 16);
        kloop(h0, h1, 0);
        for (int base = 16; base < nh; base += 16) {
            int s0 = 0, s1 = 0;
            int c0 = walksel(m0, p0, 0, base, s0, s1);
            walksel(m1, p1, c0, base, s0, s1);
            stage2(s0, s1);
            bf16x8 g0 = *reinterpret_cast<const bf16x8*>(hb + c15 * 128 + g16 * 16);
            bf16x8 g1 = *reinterpret_cast<const bf16x8*>(hb + c15 * 128 + 64 + g16 * 16);
            kloop(g0, g1, base);
        }
    }

    // epilogue
    float ps0[4] = {0,0,0,0}, ps1[4] = {0,0,0,0};
    float* stg = stage[wave];
    #pragma unroll
    for (int t = 0; t < 4; ++t) {
        const int col = t * 16 + c15;
        #pragma unroll
        for (int j = 0; j < 4; ++j) {
            float v = acc[t][j];
            v = v > 0.f ? v : 0.01f * v;
            ps0[t] += v;
            ps1[t] = fmaf(v, v, ps1[t]);
            stg[(g16 * 4 + j) * 68 + col] = v;
        }
    }
    const int mm = lane >> 2, cc0 = (lane & 3) * 16;
    float4 q0 = *reinterpret_cast<float4*>(&stg[mm * 68 + cc0]);
    float4 q1 = *reinterpret_cast<float4*>(&stg[mm * 68 + cc0 + 4]);
    float4 q2 = *reinterpret_cast<float4*>(&stg[mm * 68 + cc0 + 8]);
    float4 q3 = *reinterpret_cast<float4*>(&stg[mm * 68 + cc0 + 12]);
    uint4 o0, o1;
    o0.x = f2bf(q0.x) | ((unsigned)f2bf(q0.y) << 16);
    o0.y = f2bf(q0.z) | ((unsigned)f2bf(q0.w) << 16);
    o0.z = f2bf(q1.x) | ((unsigned)f2bf(q1.y) << 16);
    o0.w = f2bf(q1.z) | ((unsigned)f2bf(q1.w) << 16);
    o1.x = f2bf(q2.x) | ((unsigned)f2bf(q2.y) << 16);
    o1.y = f2bf(q2.z) | ((unsigned)f2bf(q2.w) << 16);
    o1.z = f2bf(q3.x) | ((unsigned)f2bf(q3.y) << 16);
    o1.w = f2bf(q3.z) | ((unsigned)f2bf(q3.w) << 16);
    uint4* dst = reinterpret_cast<uint4*>(yout + (size_t)(v16 + mm) * 64 + cc0);
    dst[0] = o0; dst[1] = o1;

    __syncthreads();
    float* lsf = &stage[0][0];                   // reuse as [16][128]
    const int r = wave * 4 + g16;
    #pragma unroll
    for (int t = 0; t < 4; ++t) {
        lsf[r * 128 + t * 16 + c15] = ps0[t];
        lsf[r * 128 + 64 + t * 16 + c15] = ps1[t];
    }
    __syncthreads();
    const int tid = threadIdx.x;
    if (tid < 128) {
        float s = 0.f;
        #pragma unroll
        for (int rr = 0; rr < 16; ++rr) s += lsf[rr * 128 + tid];
        part[(size_t)tile * 256 + (second ? 128 : 0) + tid] = s;
    }
}

// ---------- reduce partials + BN scale/shift (two layers per launch) ----------
__global__ void bnred_kernel(const float* __restrict__ part,   // [nblk][256]
                             const float* __restrict__ gA, const float* __restrict__ bA,
                             const float* __restrict__ gB, const float* __restrict__ bB,
                             float* __restrict__ scA, float* __restrict__ shA,
                             float* __restrict__ scB, float* __restrict__ shB,
                             float invN, int nblk)
{
    const int l = blockIdx.x >> 6, c = blockIdx.x & 63;   // grid 128
    const float* base = part + (size_t)(l * 2) * 64 + c;
    __shared__ float red[256][2];
    float s = 0.f, q = 0.f;
    for (int b = threadIdx.x; b < nblk; b += 256) {
        s += base[(size_t)b * 256];
        q += base[(size_t)b * 256 + 64];
    }
    red[threadIdx.x][0] = s; red[threadIdx.x][1] = q;
    __syncthreads();
    for (int off = 128; off; off >>= 1) {
        if (threadIdx.x < off) {
            red[threadIdx.x][0] += red[threadIdx.x + off][0];
            red[threadIdx.x][1] += red[threadIdx.x + off][1];
        }
        __syncthreads();
    }
    if (threadIdx.x == 0) {
        float m = red[0][0] * invN;
        float v = red[0][1] * invN - m * m;
        const float* g = l ? gB : gA;
        const float* bb = l ? bB : bA;
        float* sc = l ? scB : scA;
        float* sh = l ? shB : shA;
        float scale = g[c] / sqrtf(v + EPSF);
        sc[c] = scale;
        sh[c] = bb[c] - m * scale;
    }
}

// ---------- fold BN1/BN3 into W2/W4: tvec + bf16 B-frags for ALL 9 ks ----------
__global__ void foldpack_kernel(const float* __restrict__ W2, const float* __restrict__ W4,
                                const float* __restrict__ sc1, const float* __restrict__ sh1,
                                const float* __restrict__ sc3, const float* __restrict__ sh3,
                                float* __restrict__ t2, float* __restrict__ t4,
                                unsigned short* __restrict__ Wb2, unsigned short* __restrict__ Wb4)
{
    int i = blockIdx.x * 256 + threadIdx.x;
    if (i < 2 * 9 * 64) {
        const float* W = i < 9 * 64 ? W2 : W4;
        const float* shift = i < 9 * 64 ? sh1 : sh3;
        float* tv = i < 9 * 64 ? t2 : t4;
        int ii = i < 9 * 64 ? i : i - 9 * 64;
        int d = ii & 63, k = ii >> 6;
        float t = 0.f;
        for (int c = 0; c < 64; ++c)
            t = fmaf(shift[c], W[((size_t)k * 64 + c) * 64 + d], t);
        tv[ii] = t;
    } else {
        int p = i - 2 * 9 * 64;
        if (p >= 2 * 9 * 4096) return;
        const float* W = p < 9 * 4096 ? W2 : W4;
        const float* scale = p < 9 * 4096 ? sc1 : sc3;
        unsigned short* Wb = p < 9 * 4096 ? Wb2 : Wb4;
        int pp = p < 9 * 4096 ? p : p - 9 * 4096;
        int k = pp >> 12, rest = pp & 4095;
        int kt = rest >> 11, t = (rest >> 9) & 3, lane = (rest >> 3) & 63, j = rest & 7;
        int c = kt * 32 + (lane >> 4) * 8 + j;
        int d = t * 16 + (lane & 15);
        Wb[pp] = f2bf(scale[c] * W[((size_t)k * 64 + c) * 64 + d]);
    }
}

// ---------- final: out = BN2(y2) + BN4(y4), bf16 in, fp32 out ----------
__global__ void final_kernel(const unsigned short* __restrict__ y2,
                             const unsigned short* __restrict__ y4,
                             const float* __restrict__ sc2, const float* __restrict__ sh2,
                             const float* __restrict__ sc4, const float* __restrict__ sh4,
                             float* __restrict__ out, int n8)
{
    int i = blockIdx.x * 256 + threadIdx.x;
    if (i >= n8) return;
    const int c0 = (i & 7) * 8;
    uint4 aq = *reinterpret_cast<const uint4*>(y2 + (size_t)i * 8);
    uint4 bq = *reinterpret_cast<const uint4*>(y4 + (size_t)i * 8);
    float a[8], b[8];
    a[0] = __uint_as_float(aq.x << 16); a[1] = __uint_as_float(aq.x & 0xffff0000u);
    a[2] = __uint_as_float(aq.y << 16); a[3] = __uint_as_float(aq.y & 0xffff0000u);
    a[4] = __uint_as_float(aq.z << 16); a[5] = __uint_as_float(aq.z & 0xffff0000u);
    a[6] = __uint_as_float(aq.w << 16); a[7] = __uint_as_float(aq.w & 0xffff0000u);
    b[0] = __uint_as_float(bq.x << 16); b[1] = __uint_as_float(bq.x & 0xffff0000u);
    b[2] = __uint_as_float(bq.y << 16); b[3] = __uint_as_float(bq.y & 0xffff0000u);
    b[4] = __uint_as_float(bq.z << 16); b[5] = __uint_as_float(bq.z & 0xffff0000u);
    b[6] = __uint_as_float(bq.w << 16); b[7] = __uint_as_float(bq.w & 0xffff0000u);
    float r[8];
    #pragma unroll
    for (int j = 0; j < 8; ++j)
        r[j] = fmaf(a[j], sc2[c0 + j], sh2[c0 + j]) + fmaf(b[j], sc4[c0 + j], sh4[c0 + j]);
    float4 o0 = {r[0], r[1], r[2], r[3]};
    float4 o1 = {r[4], r[5], r[6], r[7]};
    float* po = out + (size_t)i * 8;
    *reinterpret_cast<float4*>(po) = o0;
    *reinterpret_cast<float4*>(po + 4) = o1;
}

extern "C" void kernel_launch(void* const* d_in, const int* in_sizes, int n_in,
                              void* d_out, int out_size, void* d_ws, size_t ws_size,
                              hipStream_t stream)
{
    const float* feats  = (const float*)d_in[0];
    const int*   nbr133 = (const int*)d_in[1];
    const int*   nbr313 = (const int*)d_in[2];
    const float* W1 = (const float*)d_in[3];
    const float* W2 = (const float*)d_in[4];
    const float* W3 = (const float*)d_in[5];
    const float* W4 = (const float*)d_in[6];
    const float* g0  = (const float*)d_in[7];
    const float* b0  = (const float*)d_in[8];
    const float* g02 = (const float*)d_in[9];
    const float* b02 = (const float*)d_in[10];
    const float* g1  = (const float*)d_in[11];
    const float* b1  = (const float*)d_in[12];
    const float* g2  = (const float*)d_in[13];
    const float* b2  = (const float*)d_in[14];

    const int N = in_sizes[0] / 32;
    const int ntile = N >> 6;                         // 3125 for N=200000

    char* w = (char*)d_ws;
    auto alloc = [&](size_t bytes) {
        char* p = w;
        w += (bytes + 255) & ~(size_t)255;
        return p;
    };
    unsigned short* y1 = (unsigned short*)alloc((size_t)N * 64 * 2);
    unsigned short* y3 = (unsigned short*)alloc((size_t)N * 64 * 2);
    unsigned short* y2 = (unsigned short*)alloc((size_t)N * 64 * 2);
    unsigned short* y4 = (unsigned short*)alloc((size_t)N * 64 * 2);
    float* t2 = (float*)alloc(9 * 64 * 4);
    float* t4 = (float*)alloc(9 * 64 * 4);
    unsigned short* Wb1 = (unsigned short*)alloc(9 * 4 * 64 * 8 * 2);
    unsigned short* Wb3 = (unsigned short*)alloc(9 * 4 * 64 * 8 * 2);
    unsigned short* Wb2 = (unsigned short*)alloc(9 * 2 * 4 * 64 * 8 * 2);
    unsigned short* Wb4 = (unsigned short*)alloc(9 * 2 * 4 * 64 * 8 * 2);
    float* part13 = (float*)alloc((size_t)ntile * 256 * 4);
    float* part24 = (float*)alloc((size_t)ntile * 256 * 4);
    float* scl = (float*)alloc(8 * 64 * 4);
    float *sc1 = scl,       *sh1 = scl + 64;
    float *sc3 = scl + 128, *sh3 = scl + 192;
    float *sc2 = scl + 256, *sh2 = scl + 320;
    float *sc4 = scl + 384, *sh4 = scl + 448;

    const float invN = 1.0f / (float)N;

    prep_kernel<<<(2 * 9 * 2048 + 255) / 256, 256, 0, stream>>>(W1, W3, Wb1, Wb3);

    conv13_kernel<<<ntile, 256, 0, stream>>>(feats, nbr133, nbr313, Wb1, Wb3,
                                             y1, y3, part13, N);
    bnred_kernel<<<128, 256, 0, stream>>>(part13, g0, b0, g1, b1,
                                          sc1, sh1, sc3, sh3, invN, ntile);
    foldpack_kernel<<<(2 * 9 * 64 + 2 * 9 * 4096 + 255) / 256, 256, 0, stream>>>(
        W2, W4, sc1, sh1, sc3, sh3, t2, t4, Wb2, Wb4);

    conv24_kernel<<<2 * ntile, 256, 0, stream>>>(y1, nbr313, t2, Wb2, y2,
                                                 y3, nbr133, t4, Wb4, y4,
                                                 part24, N, ntile);
    bnred_kernel<<<128, 256, 0, stream>>>(part24, g02, b02, g2, b2,
                                          sc2, sh2, sc4, sh4, invN, ntile);

    final_kernel<<<(N * 8 + 255) / 256, 256, 0, stream>>>(
        y2, y4, sc2, sh2, sc4, sh4, (float*)d_out, N * 8);
}